// Round 17
// baseline (867.623 us; speedup 1.0000x reference)
//
#include <hip/hip_runtime.h>
#include <math.h>

#define Tt 8192             // tokens (B*S)
#define Dd 1024
#define Ee 8
#define FFf 4096
#define SLOTS (Tt*2)

typedef unsigned short u16;
typedef unsigned int u32;
typedef __attribute__((ext_vector_type(8))) __bf16 bf16x8;
typedef __attribute__((ext_vector_type(4))) float f32x4;

__device__ __forceinline__ u16 f2bf(float f) {
  union { float f; u32 u; } v; v.f = f;
  u32 u = v.u;
  return (u16)((u + 0x7FFFu + ((u >> 16) & 1u)) >> 16);
}
__device__ __forceinline__ float bf2f(u16 h) {
  union { u32 u; float f; } v; v.u = ((u32)h) << 16; return v.f;
}
__device__ __forceinline__ void gl2lds16(const u16* g, u16* l) {
  __builtin_amdgcn_global_load_lds((const __attribute__((address_space(1))) void*)g,
                                   (__attribute__((address_space(3))) void*)l, 16, 0, 0);
}

// ---------------- gating (+ fused x->bf16 convert + last-block scan) ----------------
__global__ void gate_topk_kernel(const float* __restrict__ x,
                                 const float* __restrict__ gw,
                                 int* __restrict__ counts,
                                 int* __restrict__ tok_e,
                                 float* __restrict__ tok_w,
                                 u16* __restrict__ xb,
                                 int* __restrict__ offsets,
                                 int* __restrict__ cursors,
                                 int* __restrict__ done) {
  int wave = (int)((blockIdx.x * blockDim.x + threadIdx.x) >> 6);
  int lane = threadIdx.x & 63;
  const float* xrow = x + (size_t)wave * Dd;
  int d0 = lane * 16;
  const f32x4* xr4 = (const f32x4*)(xrow + d0);
  f32x4 v0 = xr4[0], v1 = xr4[1], v2 = xr4[2], v3 = xr4[3];
  float xv[16];
#pragma unroll
  for (int k = 0; k < 4; k++) { xv[k] = v0[k]; xv[4 + k] = v1[k]; xv[8 + k] = v2[k]; xv[12 + k] = v3[k]; }
  float p[Ee];
#pragma unroll
  for (int e = 0; e < Ee; e++) p[e] = 0.f;
#pragma unroll
  for (int i = 0; i < 16; i++) {
    const float* g = gw + (size_t)(d0 + i) * Ee;
#pragma unroll
    for (int e = 0; e < Ee; e++) p[e] += xv[i] * g[e];
  }
  {
    uint4 o0, o1;
    o0.x = (u32)f2bf(xv[0]) | ((u32)f2bf(xv[1]) << 16);
    o0.y = (u32)f2bf(xv[2]) | ((u32)f2bf(xv[3]) << 16);
    o0.z = (u32)f2bf(xv[4]) | ((u32)f2bf(xv[5]) << 16);
    o0.w = (u32)f2bf(xv[6]) | ((u32)f2bf(xv[7]) << 16);
    o1.x = (u32)f2bf(xv[8]) | ((u32)f2bf(xv[9]) << 16);
    o1.y = (u32)f2bf(xv[10]) | ((u32)f2bf(xv[11]) << 16);
    o1.z = (u32)f2bf(xv[12]) | ((u32)f2bf(xv[13]) << 16);
    o1.w = (u32)f2bf(xv[14]) | ((u32)f2bf(xv[15]) << 16);
    u16* dp = xb + (size_t)wave * Dd + d0;
    *(uint4*)dp = o0;
    *(uint4*)(dp + 8) = o1;
  }
#pragma unroll
  for (int e = 0; e < Ee; e++) {
    for (int off = 32; off > 0; off >>= 1) p[e] += __shfl_xor(p[e], off, 64);
  }
  if (lane == 0) {
    int e0 = 0; float v0s = p[0];
#pragma unroll
    for (int e = 1; e < Ee; e++) if (p[e] > v0s) { v0s = p[e]; e0 = e; }
    int e1 = -1; float v1s = -INFINITY;
#pragma unroll
    for (int e = 0; e < Ee; e++) if (e != e0 && p[e] > v1s) { v1s = p[e]; e1 = e; }
    float w0 = 1.f / (1.f + expf(v1s - v0s));
    float w1 = 1.f - w0;
    tok_e[wave * 2 + 0] = e0; tok_e[wave * 2 + 1] = e1;
    tok_w[wave * 2 + 0] = w0; tok_w[wave * 2 + 1] = w1;
    atomicAdd(&counts[e0], 1);
    atomicAdd(&counts[e1], 1);
  }
  // last-block scan (saves a launch): counts -> offsets/cursors
  __syncthreads();
  if (threadIdx.x == 0) {
    __threadfence();
    int t = atomicAdd(done, 1);
    if (t == (int)gridDim.x - 1) {
      __threadfence();
      int acc = 0;
      for (int e = 0; e < Ee; e++) { offsets[e] = acc; cursors[e] = acc; acc += counts[e]; }
    }
  }
}

// ---------------- weight transpose+convert, 128x128 tiles ----------------
__global__ __launch_bounds__(256) void wconv_kernel(const float* __restrict__ src,
                                                    u16* __restrict__ dst, int R, int C) {
  __shared__ float t[128][129];
  int e = blockIdx.z;
  size_t ebase = (size_t)e * R * C;
  int r0 = blockIdx.y * 128, c0 = blockIdx.x * 128;
  int tid = threadIdx.x;
  int rrow = tid >> 5, rcol = (tid & 31) * 4;
#pragma unroll
  for (int p = 0; p < 16; p++) {
    int row = rrow + p * 8;
    f32x4 v = *(const f32x4*)(src + ebase + (size_t)(r0 + row) * C + c0 + rcol);
    t[row][rcol] = v[0]; t[row][rcol + 1] = v[1]; t[row][rcol + 2] = v[2]; t[row][rcol + 3] = v[3];
  }
  __syncthreads();
  int wcol = tid >> 4, rseg = (tid & 15) * 8;
#pragma unroll
  for (int q = 0; q < 8; q++) {
    int cp = wcol + q * 16;
    float f[8];
#pragma unroll
    for (int i = 0; i < 8; i++) f[i] = t[rseg + i][cp];
    uint4 o;
    o.x = (u32)f2bf(f[0]) | ((u32)f2bf(f[1]) << 16);
    o.y = (u32)f2bf(f[2]) | ((u32)f2bf(f[3]) << 16);
    o.z = (u32)f2bf(f[4]) | ((u32)f2bf(f[5]) << 16);
    o.w = (u32)f2bf(f[6]) | ((u32)f2bf(f[7]) << 16);
    *(uint4*)(dst + ebase + (size_t)(c0 + cp) * R + r0 + rseg) = o;
  }
}

// ---------------- merged wconv (128x128 tiles): z 0-7 w1, 8-15 w2 ----------------
__global__ __launch_bounds__(256) void wconv2_kernel(const float* __restrict__ w1,
                                                     const float* __restrict__ w2,
                                                     u16* __restrict__ dst1,
                                                     u16* __restrict__ dst2) {
  __shared__ float t[128][129];
  int half = blockIdx.z >> 3;
  int e = blockIdx.z & 7;
  const float* src = half ? w2 : w1;
  u16* dst = half ? dst2 : dst1;
  int R = half ? FFf : Dd;
  int C = half ? Dd : FFf;
  int bx = blockIdx.x;
  int cblk = half ? (bx & 7) : (bx & 31);
  int rblk = half ? (bx >> 3) : (bx >> 5);
  size_t ebase = (size_t)e * R * C;
  int r0 = rblk * 128, c0 = cblk * 128;
  int tid = threadIdx.x;
  int rrow = tid >> 5, rcol = (tid & 31) * 4;
#pragma unroll
  for (int p = 0; p < 16; p++) {
    int row = rrow + p * 8;
    f32x4 v = *(const f32x4*)(src + ebase + (size_t)(r0 + row) * C + c0 + rcol);
    t[row][rcol] = v[0]; t[row][rcol + 1] = v[1]; t[row][rcol + 2] = v[2]; t[row][rcol + 3] = v[3];
  }
  __syncthreads();
  int wcol = tid >> 4, rseg = (tid & 15) * 8;
#pragma unroll
  for (int q = 0; q < 8; q++) {
    int cp = wcol + q * 16;
    float f[8];
#pragma unroll
    for (int i = 0; i < 8; i++) f[i] = t[rseg + i][cp];
    uint4 o;
    o.x = (u32)f2bf(f[0]) | ((u32)f2bf(f[1]) << 16);
    o.y = (u32)f2bf(f[2]) | ((u32)f2bf(f[3]) << 16);
    o.z = (u32)f2bf(f[4]) | ((u32)f2bf(f[5]) << 16);
    o.w = (u32)f2bf(f[6]) | ((u32)f2bf(f[7]) << 16);
    *(uint4*)(dst + ebase + (size_t)(c0 + cp) * R + r0 + rseg) = o;
  }
}

// ---------------- scatter tokens into per-expert slot lists ----------------
__global__ void scatter_kernel(const int* __restrict__ tok_e, const float* __restrict__ tok_w,
                               int* __restrict__ cursors,
                               int* __restrict__ slot_token, float* __restrict__ slot_w,
                               int* __restrict__ tok_slot) {
  int t = blockIdx.x * blockDim.x + threadIdx.x;
  if (t >= Tt) return;
#pragma unroll
  for (int k = 0; k < 2; k++) {
    int e = tok_e[t * 2 + k];
    int pos = atomicAdd(&cursors[e], 1);
    slot_token[pos] = t;
    slot_w[pos] = tok_w[t * 2 + k];
    tok_slot[t * 2 + k] = pos;
  }
}

// =====================================================================
// 4-phase 256x256 grouped GEMM — main loop FROZEN (R12 form); R16
// staged epilogue (EPI 0/1), direct atomic epilogue (EPI 2).
// All three instantiations kept compiled identically (rule #19).
// =====================================================================
#define MFMA16(H)                                                                 \
  do {                                                                            \
    acc[H][0][0] = __builtin_amdgcn_mfma_f32_16x16x32_bf16(a0, b0, acc[H][0][0], 0, 0, 0); \
    acc[H][0][1] = __builtin_amdgcn_mfma_f32_16x16x32_bf16(a0, b1, acc[H][0][1], 0, 0, 0); \
    acc[H][0][2] = __builtin_amdgcn_mfma_f32_16x16x32_bf16(a0, b2, acc[H][0][2], 0, 0, 0); \
    acc[H][0][3] = __builtin_amdgcn_mfma_f32_16x16x32_bf16(a0, b3, acc[H][0][3], 0, 0, 0); \
    acc[H][1][0] = __builtin_amdgcn_mfma_f32_16x16x32_bf16(a1, b0, acc[H][1][0], 0, 0, 0); \
    acc[H][1][1] = __builtin_amdgcn_mfma_f32_16x16x32_bf16(a1, b1, acc[H][1][1], 0, 0, 0); \
    acc[H][1][2] = __builtin_amdgcn_mfma_f32_16x16x32_bf16(a1, b2, acc[H][1][2], 0, 0, 0); \
    acc[H][1][3] = __builtin_amdgcn_mfma_f32_16x16x32_bf16(a1, b3, acc[H][1][3], 0, 0, 0); \
    acc[H][2][0] = __builtin_amdgcn_mfma_f32_16x16x32_bf16(a2, b0, acc[H][2][0], 0, 0, 0); \
    acc[H][2][1] = __builtin_amdgcn_mfma_f32_16x16x32_bf16(a2, b1, acc[H][2][1], 0, 0, 0); \
    acc[H][2][2] = __builtin_amdgcn_mfma_f32_16x16x32_bf16(a2, b2, acc[H][2][2], 0, 0, 0); \
    acc[H][2][3] = __builtin_amdgcn_mfma_f32_16x16x32_bf16(a2, b3, acc[H][2][3], 0, 0, 0); \
    acc[H][3][0] = __builtin_amdgcn_mfma_f32_16x16x32_bf16(a3, b0, acc[H][3][0], 0, 0, 0); \
    acc[H][3][1] = __builtin_amdgcn_mfma_f32_16x16x32_bf16(a3, b1, acc[H][3][1], 0, 0, 0); \
    acc[H][3][2] = __builtin_amdgcn_mfma_f32_16x16x32_bf16(a3, b2, acc[H][3][2], 0, 0, 0); \
    acc[H][3][3] = __builtin_amdgcn_mfma_f32_16x16x32_bf16(a3, b3, acc[H][3][3], 0, 0, 0); \
  } while (0)

template<int KDIM, int NDIM, int EPI, int GATHER>
__device__ __forceinline__ void moe_body(
    const u16* __restrict__ A, const u16* __restrict__ BT,
    const float* __restrict__ bias,
    const int* __restrict__ offsets, const int* __restrict__ counts,
    const int* __restrict__ slot_token, const float* __restrict__ slot_w,
    u16* __restrict__ O16, float* __restrict__ Of) {
  constexpr int NT = KDIM / 64;
  int e = blockIdx.z;
  int cnt = counts[e];
  int rb = blockIdx.y;
  if (rb * 256 >= cnt) return;
  int off = offsets[e];
  int n0 = blockIdx.x * 256;

  __shared__ u16 S[65536];   // 128 KiB

  int tid = threadIdx.x;
  int lane = tid & 63, wave = tid >> 6;
  int wr = wave >> 2, wc = wave & 3;
  int lr = lane & 15, g = lane >> 4;

  const u16* BTe = BT + (size_t)e * NDIM * KDIM;

  const u16* aSrc[2][2];
  const u16* bSrc[2][2];
  int amax = off + cnt - 1;
#pragma unroll
  for (int h = 0; h < 2; h++)
#pragma unroll
    for (int s = 0; s < 2; s++) {
      int c = tid + s * 512;
      int lc = c ^ (((c >> 5) & 1) << 1);
      int ks = lc >> 9, rl = (lc >> 2) & 127, seg = lc & 3;
      int slotRow = off + rb * 256 + h * 128 + rl;
      if (slotRow > amax) slotRow = amax;
      int arow = GATHER ? slot_token[slotRow] : slotRow;
      aSrc[h][s] = A + (size_t)arow * KDIM + ks * 32 + seg * 8;
    }
#pragma unroll
  for (int ks = 0; ks < 2; ks++)
#pragma unroll
    for (int s = 0; s < 2; s++) {
      int c = tid + s * 512;
      int lc = c ^ (((c >> 5) & 1) << 1);
      int row = lc >> 2, seg = lc & 3;
      bSrc[ks][s] = BTe + (size_t)(n0 + row) * KDIM + ks * 32 + seg * 8;
    }

  auto stA = [&](int u, int h) {
    u16* d = &S[(u & 1) * 16384 + h * 8192 + wave * 512];
    gl2lds16(aSrc[h][0] + (size_t)u * 64, d);
    gl2lds16(aSrc[h][1] + (size_t)u * 64, d + 4096);
  };
  auto stB = [&](int u, int ks) {
    u16* d = &S[32768 + (u & 1) * 16384 + ks * 8192 + wave * 512];
    gl2lds16(bSrc[ks][0] + (size_t)u * 64, d);
    gl2lds16(bSrc[ks][1] + (size_t)u * 64, d + 4096);
  };
  auto rdA = [&](int dbuf, int hm, int ks, int i) -> bf16x8 {
    int rl = wr * 64 + i * 16 + lr;
    int logb = ks * 8192 + rl * 64 + g * 16;
    int phys = logb ^ (((rl >> 3) & 1) << 5);
    return *reinterpret_cast<const bf16x8*>(&S[dbuf * 16384 + hm * 8192 + (phys >> 1)]);
  };
  auto rdB = [&](int dbuf, int ks, int j) -> bf16x8 {
    int row = wc * 64 + j * 16 + lr;
    int logb = row * 64 + g * 16;
    int phys = logb ^ (((row >> 3) & 1) << 5);
    return *reinterpret_cast<const bf16x8*>(&S[32768 + dbuf * 16384 + ks * 8192 + (phys >> 1)]);
  };

  f32x4 acc[2][4][4];
#pragma unroll
  for (int h = 0; h < 2; h++)
#pragma unroll
    for (int i = 0; i < 4; i++)
#pragma unroll
      for (int j = 0; j < 4; j++) acc[h][i][j] = (f32x4)(0.0f);

  // prologue: tile0 {Bk0,A0,A1,Bk1}, tile1 {Bk0,A0}; tile0 landed via vmcnt(4)
  stB(0, 0); stA(0, 0); stA(0, 1); stB(0, 1);
  stB(1, 0); stA(1, 0);
  asm volatile("s_waitcnt vmcnt(4)" ::: "memory");
  __builtin_amdgcn_s_barrier();

  bf16x8 b0, b1, b2, b3;
#pragma unroll 2
  for (int t = 0; t < NT; ++t) {
    int dbuf = t & 1;
    // ---- P1 (hm=0, ks=0): stage (t+1).A1
    {
      bf16x8 a0 = rdA(dbuf, 0, 0, 0), a1 = rdA(dbuf, 0, 0, 1),
             a2 = rdA(dbuf, 0, 0, 2), a3 = rdA(dbuf, 0, 0, 3);
      b0 = rdB(dbuf, 0, 0); b1 = rdB(dbuf, 0, 1); b2 = rdB(dbuf, 0, 2); b3 = rdB(dbuf, 0, 3);
      if (t + 1 < NT) stA(t + 1, 1);
      __builtin_amdgcn_s_barrier();
      asm volatile("s_waitcnt lgkmcnt(0)" ::: "memory");
      __builtin_amdgcn_sched_barrier(0);
      __builtin_amdgcn_s_setprio(1);
      MFMA16(0);
      __builtin_amdgcn_s_setprio(0);
      __builtin_amdgcn_s_barrier();
    }
    // ---- P2 (hm=1, ks=0): stage (t+1).Bk1 ; vmcnt(6)
    {
      bf16x8 a0 = rdA(dbuf, 1, 0, 0), a1 = rdA(dbuf, 1, 0, 1),
             a2 = rdA(dbuf, 1, 0, 2), a3 = rdA(dbuf, 1, 0, 3);
      if (t + 1 < NT) {
        stB(t + 1, 1);
        asm volatile("s_waitcnt vmcnt(6)" ::: "memory");
      }
      __builtin_amdgcn_s_barrier();
      asm volatile("s_waitcnt lgkmcnt(0)" ::: "memory");
      __builtin_amdgcn_sched_barrier(0);
      __builtin_amdgcn_s_setprio(1);
      MFMA16(1);
      __builtin_amdgcn_s_setprio(0);
      __builtin_amdgcn_s_barrier();
    }
    // ---- P3 (hm=0, ks=1): stage (t+2).Bk0
    {
      bf16x8 a0 = rdA(dbuf, 0, 1, 0), a1 = rdA(dbuf, 0, 1, 1),
             a2 = rdA(dbuf, 0, 1, 2), a3 = rdA(dbuf, 0, 1, 3);
      b0 = rdB(dbuf, 1, 0); b1 = rdB(dbuf, 1, 1); b2 = rdB(dbuf, 1, 2); b3 = rdB(dbuf, 1, 3);
      if (t + 2 < NT) stB(t + 2, 0);
      __builtin_amdgcn_s_barrier();
      asm volatile("s_waitcnt lgkmcnt(0)" ::: "memory");
      __builtin_amdgcn_sched_barrier(0);
      __builtin_amdgcn_s_setprio(1);
      MFMA16(0);
      __builtin_amdgcn_s_setprio(0);
      __builtin_amdgcn_s_barrier();
    }
    // ---- P4 (hm=1, ks=1): stage (t+2).A0 ; vmcnt(6) (tail: drain)
    {
      bf16x8 a0 = rdA(dbuf, 1, 1, 0), a1 = rdA(dbuf, 1, 1, 1),
             a2 = rdA(dbuf, 1, 1, 2), a3 = rdA(dbuf, 1, 1, 3);
      if (t + 2 < NT) {
        stA(t + 2, 0);
        asm volatile("s_waitcnt vmcnt(6)" ::: "memory");
      } else if (t + 1 < NT) {
        asm volatile("s_waitcnt vmcnt(0)" ::: "memory");
      }
      __builtin_amdgcn_s_barrier();
      asm volatile("s_waitcnt lgkmcnt(0)" ::: "memory");
      __builtin_amdgcn_sched_barrier(0);
      __builtin_amdgcn_s_setprio(1);
      MFMA16(1);
      __builtin_amdgcn_s_setprio(0);
      __builtin_amdgcn_s_barrier();
    }
  }

  int rlim = cnt - rb * 256;
  if (EPI == 2) {
#pragma unroll
    for (int hm = 0; hm < 2; hm++)
#pragma unroll
      for (int i = 0; i < 4; i++)
#pragma unroll
        for (int q = 0; q < 4; q++) {
          int m = hm * 128 + wr * 64 + i * 16 + g * 4 + q;
          if (m < rlim) {
            int slot = off + rb * 256 + m;
#pragma unroll
            for (int j = 0; j < 4; j++) {
              int n = n0 + wc * 64 + j * 16 + lr;
              float v = acc[hm][i][j][q] + bias[e * NDIM + n];
              atomicAdd(Of + (size_t)slot_token[slot] * NDIM + n, v * slot_w[slot]);
            }
          }
        }
  } else {
    // staged epilogue: scale/activate in regs -> LDS (n XOR-swizzled) -> coalesced stores
#pragma unroll
    for (int hm = 0; hm < 2; hm++)
#pragma unroll
      for (int i = 0; i < 4; i++)
#pragma unroll
        for (int q = 0; q < 4; q++) {
          int m = hm * 128 + wr * 64 + i * 16 + g * 4 + q;
          int slot = off + rb * 256 + m;
          float sw = (EPI == 1) ? slot_w[slot] : 0.f;
#pragma unroll
          for (int j = 0; j < 4; j++) {
            int n = wc * 64 + j * 16 + lr;
            float v = acc[hm][i][j][q] + bias[e * NDIM + n0 + n];
            if (EPI == 0) v = v / (1.f + __expf(-v));   // silu (fast exp)
            else          v = v * sw;
            int pn = n ^ (((m >> 2) & 7) << 3);
            S[m * 256 + pn] = f2bf(v);
          }
        }
    __builtin_amdgcn_s_barrier();
    int rgrp = tid >> 5;
    int cs = (tid & 31) * 8;
#pragma unroll
    for (int p = 0; p < 16; p++) {
      int m = rgrp * 16 + p;
      if (m < rlim) {
        int slot = off + rb * 256 + m;
        int pc = cs ^ (((m >> 2) & 7) << 3);
        uint4 vv = *(const uint4*)&S[m * 256 + pc];
        *(uint4*)(O16 + (size_t)slot * NDIM + n0 + cs) = vv;
      }
    }
  }
}

__global__ __launch_bounds__(512, 2) void moe_g1_kernel(
    const u16* __restrict__ A, const u16* __restrict__ BT, const float* __restrict__ bias,
    const int* __restrict__ offsets, const int* __restrict__ counts,
    const int* __restrict__ slot_token, const float* __restrict__ slot_w,
    u16* __restrict__ O16) {
  moe_body<Dd, FFf, 0, 1>(A, BT, bias, offsets, counts, slot_token, slot_w, O16, nullptr);
}
__global__ __launch_bounds__(512, 2) void moe_g2_kernel(
    const u16* __restrict__ A, const u16* __restrict__ BT, const float* __restrict__ bias,
    const int* __restrict__ offsets, const int* __restrict__ counts,
    const int* __restrict__ slot_token, const float* __restrict__ slot_w,
    u16* __restrict__ O16) {
  moe_body<FFf, Dd, 1, 0>(A, BT, bias, offsets, counts, slot_token, slot_w, O16, nullptr);
}
__global__ __launch_bounds__(512, 2) void moe_g2_atomic_kernel(
    const u16* __restrict__ A, const u16* __restrict__ BT, const float* __restrict__ bias,
    const int* __restrict__ offsets, const int* __restrict__ counts,
    const int* __restrict__ slot_token, const float* __restrict__ slot_w,
    float* __restrict__ Of) {
  moe_body<FFf, Dd, 2, 0>(A, BT, bias, offsets, counts, slot_token, slot_w, nullptr, Of);
}

// ---------------- combine (kept for fallback tier) ----------------
__global__ void combine_kernel(const u16* __restrict__ y, const int* __restrict__ tok_slot,
                               float* __restrict__ out) {
  int gid = blockIdx.x * blockDim.x + threadIdx.x;
  int t = gid >> 7;
  int seg = gid & 127;
  int s0 = tok_slot[t * 2 + 0], s1 = tok_slot[t * 2 + 1];
  uint4 a = *(const uint4*)(y + (size_t)s0 * Dd + seg * 8);
  uint4 b = *(const uint4*)(y + (size_t)s1 * Dd + seg * 8);
  f32x4 o0, o1;
  o0[0] = bf2f((u16)a.x) + bf2f((u16)b.x);
  o0[1] = bf2f((u16)(a.x >> 16)) + bf2f((u16)(b.x >> 16));
  o0[2] = bf2f((u16)a.y) + bf2f((u16)b.y);
  o0[3] = bf2f((u16)(a.y >> 16)) + bf2f((u16)(b.y >> 16));
  o1[0] = bf2f((u16)a.z) + bf2f((u16)b.z);
  o1[1] = bf2f((u16)(a.z >> 16)) + bf2f((u16)(b.z >> 16));
  o1[2] = bf2f((u16)a.w) + bf2f((u16)b.w);
  o1[3] = bf2f((u16)(a.w >> 16)) + bf2f((u16)(b.w >> 16));
  float* op = out + (size_t)t * Dd + seg * 8;
  *(f32x4*)op = o0;
  *(f32x4*)(op + 4) = o1;
}

extern "C" void kernel_launch(void* const* d_in, const int* in_sizes, int n_in,
                              void* d_out, int out_size, void* d_ws, size_t ws_size,
                              hipStream_t stream) {
  const float* x  = (const float*)d_in[0];
  const float* gw = (const float*)d_in[1];
  const float* w1 = (const float*)d_in[2];
  const float* b1 = (const float*)d_in[3];
  const float* w2 = (const float*)d_in[4];
  const float* b2 = (const float*)d_in[5];
  float* out = (float*)d_out;

  char* ws = (char*)d_ws;
  size_t off_counts = 0;
  size_t off_offsets = 256;
  size_t off_cursors = 512;
  size_t off_done = 768;
  size_t off_tok_e = 1024;
  size_t off_tok_w     = off_tok_e + (size_t)Tt * 2 * 4;
  size_t off_tok_slot  = off_tok_w + (size_t)Tt * 2 * 4;
  size_t off_slot_token= off_tok_slot + (size_t)Tt * 2 * 4;
  size_t off_slot_w    = off_slot_token + (size_t)SLOTS * 4;
  size_t off_xb        = off_slot_w + (size_t)SLOTS * 4;
  size_t off_h         = off_xb + (size_t)Tt * Dd * 2;
  size_t off_wT        = off_h + (size_t)SLOTS * FFf * 2;
  size_t off_wT2       = off_wT + (size_t)Ee * Dd * FFf * 2;
  size_t need_base     = off_wT2;                                  // atomic path, wT reuse
  size_t need_merged   = off_wT2 + (size_t)Ee * Dd * FFf * 2;      // atomic path, wT2
  if (ws_size < need_base) return;  // fail visibly, no OOB
  int merged = (ws_size >= need_merged) ? 1 : 0;

  int* counts     = (int*)(ws + off_counts);
  int* offsets    = (int*)(ws + off_offsets);
  int* cursors    = (int*)(ws + off_cursors);
  int* done       = (int*)(ws + off_done);
  int* tok_e      = (int*)(ws + off_tok_e);
  float* tok_w    = (float*)(ws + off_tok_w);
  int* tok_slot   = (int*)(ws + off_tok_slot);
  int* slot_token = (int*)(ws + off_slot_token);
  float* slot_w   = (float*)(ws + off_slot_w);
  u16* xb         = (u16*)(ws + off_xb);
  u16* h          = (u16*)(ws + off_h);
  u16* wT         = (u16*)(ws + off_wT);
  u16* wT2        = (u16*)(ws + off_wT2);

  hipMemsetAsync(ws, 0, 1024, stream);                                 // counts/offsets/cursors/done
  hipMemsetAsync(d_out, 0, (size_t)out_size * sizeof(float), stream);  // atomic accum target

  gate_topk_kernel<<<Tt / 4, 256, 0, stream>>>(x, gw, counts, tok_e, tok_w, xb,
                                               offsets, cursors, done);
  scatter_kernel<<<Tt / 256, 256, 0, stream>>>(tok_e, tok_w, cursors, slot_token, slot_w, tok_slot);

  if (merged) {
    dim3 gc(256, 1, 16);
    wconv2_kernel<<<gc, 256, 0, stream>>>(w1, w2, wT, wT2);
    {
      dim3 g1(FFf / 256, Tt / 256, Ee);
      moe_g1_kernel<<<g1, 512, 0, stream>>>(xb, wT, b1, offsets, counts,
                                            slot_token, slot_w, h);
    }
    {
      dim3 g2(Dd / 256, Tt / 256, Ee);
      moe_g2_atomic_kernel<<<g2, 512, 0, stream>>>(h, wT2, b2, offsets, counts,
                                                   slot_token, slot_w, out);
    }
  } else {
    {
      dim3 gc(FFf / 128, Dd / 128, Ee);
      wconv_kernel<<<gc, 256, 0, stream>>>(w1, wT, Dd, FFf);
    }
    {
      dim3 g1(FFf / 256, Tt / 256, Ee);
      moe_g1_kernel<<<g1, 512, 0, stream>>>(xb, wT, b1, offsets, counts,
                                            slot_token, slot_w, h);
    }
    {
      dim3 gc(Dd / 128, FFf / 128, Ee);
      wconv_kernel<<<gc, 256, 0, stream>>>(w2, wT, FFf, Dd);
    }
    {
      dim3 g2(Dd / 256, Tt / 256, Ee);
      moe_g2_atomic_kernel<<<g2, 512, 0, stream>>>(h, wT, b2, offsets, counts,
                                                   slot_token, slot_w, out);
    }
  }
}

// Round 18
// 762.828 us; speedup vs baseline: 1.1374x; 1.1374x over previous
//
#include <hip/hip_runtime.h>
#include <math.h>

#define Tt 8192             // tokens (B*S)
#define Dd 1024
#define Ee 8
#define FFf 4096
#define SLOTS (Tt*2)

typedef unsigned short u16;
typedef unsigned int u32;
typedef __attribute__((ext_vector_type(8))) __bf16 bf16x8;
typedef __attribute__((ext_vector_type(4))) float f32x4;

__device__ __forceinline__ u16 f2bf(float f) {
  union { float f; u32 u; } v; v.f = f;
  u32 u = v.u;
  return (u16)((u + 0x7FFFu + ((u >> 16) & 1u)) >> 16);
}
__device__ __forceinline__ float bf2f(u16 h) {
  union { u32 u; float f; } v; v.u = ((u32)h) << 16; return v.f;
}
__device__ __forceinline__ void gl2lds16(const u16* g, u16* l) {
  __builtin_amdgcn_global_load_lds((const __attribute__((address_space(1))) void*)g,
                                   (__attribute__((address_space(3))) void*)l, 16, 0, 0);
}

// ---------------- gating (+ fused x->bf16 convert + last-block scan) ----------------
__global__ void gate_topk_kernel(const float* __restrict__ x,
                                 const float* __restrict__ gw,
                                 int* __restrict__ counts,
                                 int* __restrict__ tok_e,
                                 float* __restrict__ tok_w,
                                 u16* __restrict__ xb,
                                 int* __restrict__ offsets,
                                 int* __restrict__ cursors,
                                 int* __restrict__ done) {
  int wave = (int)((blockIdx.x * blockDim.x + threadIdx.x) >> 6);
  int lane = threadIdx.x & 63;
  const float* xrow = x + (size_t)wave * Dd;
  int d0 = lane * 16;
  const f32x4* xr4 = (const f32x4*)(xrow + d0);
  f32x4 v0 = xr4[0], v1 = xr4[1], v2 = xr4[2], v3 = xr4[3];
  float xv[16];
#pragma unroll
  for (int k = 0; k < 4; k++) { xv[k] = v0[k]; xv[4 + k] = v1[k]; xv[8 + k] = v2[k]; xv[12 + k] = v3[k]; }
  float p[Ee];
#pragma unroll
  for (int e = 0; e < Ee; e++) p[e] = 0.f;
#pragma unroll
  for (int i = 0; i < 16; i++) {
    const float* g = gw + (size_t)(d0 + i) * Ee;
#pragma unroll
    for (int e = 0; e < Ee; e++) p[e] += xv[i] * g[e];
  }
  {
    uint4 o0, o1;
    o0.x = (u32)f2bf(xv[0]) | ((u32)f2bf(xv[1]) << 16);
    o0.y = (u32)f2bf(xv[2]) | ((u32)f2bf(xv[3]) << 16);
    o0.z = (u32)f2bf(xv[4]) | ((u32)f2bf(xv[5]) << 16);
    o0.w = (u32)f2bf(xv[6]) | ((u32)f2bf(xv[7]) << 16);
    o1.x = (u32)f2bf(xv[8]) | ((u32)f2bf(xv[9]) << 16);
    o1.y = (u32)f2bf(xv[10]) | ((u32)f2bf(xv[11]) << 16);
    o1.z = (u32)f2bf(xv[12]) | ((u32)f2bf(xv[13]) << 16);
    o1.w = (u32)f2bf(xv[14]) | ((u32)f2bf(xv[15]) << 16);
    u16* dp = xb + (size_t)wave * Dd + d0;
    *(uint4*)dp = o0;
    *(uint4*)(dp + 8) = o1;
  }
#pragma unroll
  for (int e = 0; e < Ee; e++) {
    for (int off = 32; off > 0; off >>= 1) p[e] += __shfl_xor(p[e], off, 64);
  }
  if (lane == 0) {
    int e0 = 0; float v0s = p[0];
#pragma unroll
    for (int e = 1; e < Ee; e++) if (p[e] > v0s) { v0s = p[e]; e0 = e; }
    int e1 = -1; float v1s = -INFINITY;
#pragma unroll
    for (int e = 0; e < Ee; e++) if (e != e0 && p[e] > v1s) { v1s = p[e]; e1 = e; }
    float w0 = 1.f / (1.f + expf(v1s - v0s));
    float w1 = 1.f - w0;
    tok_e[wave * 2 + 0] = e0; tok_e[wave * 2 + 1] = e1;
    tok_w[wave * 2 + 0] = w0; tok_w[wave * 2 + 1] = w1;
    atomicAdd(&counts[e0], 1);
    atomicAdd(&counts[e1], 1);
  }
  // last-block scan (saves a launch): counts -> offsets/cursors
  __syncthreads();
  if (threadIdx.x == 0) {
    __threadfence();
    int t = atomicAdd(done, 1);
    if (t == (int)gridDim.x - 1) {
      __threadfence();
      int acc = 0;
      for (int e = 0; e < Ee; e++) { offsets[e] = acc; cursors[e] = acc; acc += counts[e]; }
    }
  }
}

// ---------------- weight transpose+convert, 128x128 tiles ----------------
__global__ __launch_bounds__(256) void wconv_kernel(const float* __restrict__ src,
                                                    u16* __restrict__ dst, int R, int C) {
  __shared__ float t[128][129];
  int e = blockIdx.z;
  size_t ebase = (size_t)e * R * C;
  int r0 = blockIdx.y * 128, c0 = blockIdx.x * 128;
  int tid = threadIdx.x;
  int rrow = tid >> 5, rcol = (tid & 31) * 4;
#pragma unroll
  for (int p = 0; p < 16; p++) {
    int row = rrow + p * 8;
    f32x4 v = *(const f32x4*)(src + ebase + (size_t)(r0 + row) * C + c0 + rcol);
    t[row][rcol] = v[0]; t[row][rcol + 1] = v[1]; t[row][rcol + 2] = v[2]; t[row][rcol + 3] = v[3];
  }
  __syncthreads();
  int wcol = tid >> 4, rseg = (tid & 15) * 8;
#pragma unroll
  for (int q = 0; q < 8; q++) {
    int cp = wcol + q * 16;
    float f[8];
#pragma unroll
    for (int i = 0; i < 8; i++) f[i] = t[rseg + i][cp];
    uint4 o;
    o.x = (u32)f2bf(f[0]) | ((u32)f2bf(f[1]) << 16);
    o.y = (u32)f2bf(f[2]) | ((u32)f2bf(f[3]) << 16);
    o.z = (u32)f2bf(f[4]) | ((u32)f2bf(f[5]) << 16);
    o.w = (u32)f2bf(f[6]) | ((u32)f2bf(f[7]) << 16);
    *(uint4*)(dst + ebase + (size_t)(c0 + cp) * R + r0 + rseg) = o;
  }
}

// ---------------- merged wconv (128x128 tiles): z 0-7 w1, 8-15 w2 ----------------
__global__ __launch_bounds__(256) void wconv2_kernel(const float* __restrict__ w1,
                                                     const float* __restrict__ w2,
                                                     u16* __restrict__ dst1,
                                                     u16* __restrict__ dst2) {
  __shared__ float t[128][129];
  int half = blockIdx.z >> 3;
  int e = blockIdx.z & 7;
  const float* src = half ? w2 : w1;
  u16* dst = half ? dst2 : dst1;
  int R = half ? FFf : Dd;
  int C = half ? Dd : FFf;
  int bx = blockIdx.x;
  int cblk = half ? (bx & 7) : (bx & 31);
  int rblk = half ? (bx >> 3) : (bx >> 5);
  size_t ebase = (size_t)e * R * C;
  int r0 = rblk * 128, c0 = cblk * 128;
  int tid = threadIdx.x;
  int rrow = tid >> 5, rcol = (tid & 31) * 4;
#pragma unroll
  for (int p = 0; p < 16; p++) {
    int row = rrow + p * 8;
    f32x4 v = *(const f32x4*)(src + ebase + (size_t)(r0 + row) * C + c0 + rcol);
    t[row][rcol] = v[0]; t[row][rcol + 1] = v[1]; t[row][rcol + 2] = v[2]; t[row][rcol + 3] = v[3];
  }
  __syncthreads();
  int wcol = tid >> 4, rseg = (tid & 15) * 8;
#pragma unroll
  for (int q = 0; q < 8; q++) {
    int cp = wcol + q * 16;
    float f[8];
#pragma unroll
    for (int i = 0; i < 8; i++) f[i] = t[rseg + i][cp];
    uint4 o;
    o.x = (u32)f2bf(f[0]) | ((u32)f2bf(f[1]) << 16);
    o.y = (u32)f2bf(f[2]) | ((u32)f2bf(f[3]) << 16);
    o.z = (u32)f2bf(f[4]) | ((u32)f2bf(f[5]) << 16);
    o.w = (u32)f2bf(f[6]) | ((u32)f2bf(f[7]) << 16);
    *(uint4*)(dst + ebase + (size_t)(c0 + cp) * R + r0 + rseg) = o;
  }
}

// ---------------- scatter tokens into per-expert slot lists ----------------
__global__ void scatter_kernel(const int* __restrict__ tok_e, const float* __restrict__ tok_w,
                               int* __restrict__ cursors,
                               int* __restrict__ slot_token, float* __restrict__ slot_w,
                               int* __restrict__ tok_slot) {
  int t = blockIdx.x * blockDim.x + threadIdx.x;
  if (t >= Tt) return;
#pragma unroll
  for (int k = 0; k < 2; k++) {
    int e = tok_e[t * 2 + k];
    int pos = atomicAdd(&cursors[e], 1);
    slot_token[pos] = t;
    slot_w[pos] = tok_w[t * 2 + k];
    tok_slot[t * 2 + k] = pos;
  }
}

// =====================================================================
// 4-phase 256x256 grouped GEMM — main loop FROZEN (R12 form); R16
// staged epilogue (EPI 0/1), atomic epilogue (EPI 2, fallback only —
// R17 measured atomics at +110us vs staged+combine).
// =====================================================================
#define MFMA16(H)                                                                 \
  do {                                                                            \
    acc[H][0][0] = __builtin_amdgcn_mfma_f32_16x16x32_bf16(a0, b0, acc[H][0][0], 0, 0, 0); \
    acc[H][0][1] = __builtin_amdgcn_mfma_f32_16x16x32_bf16(a0, b1, acc[H][0][1], 0, 0, 0); \
    acc[H][0][2] = __builtin_amdgcn_mfma_f32_16x16x32_bf16(a0, b2, acc[H][0][2], 0, 0, 0); \
    acc[H][0][3] = __builtin_amdgcn_mfma_f32_16x16x32_bf16(a0, b3, acc[H][0][3], 0, 0, 0); \
    acc[H][1][0] = __builtin_amdgcn_mfma_f32_16x16x32_bf16(a1, b0, acc[H][1][0], 0, 0, 0); \
    acc[H][1][1] = __builtin_amdgcn_mfma_f32_16x16x32_bf16(a1, b1, acc[H][1][1], 0, 0, 0); \
    acc[H][1][2] = __builtin_amdgcn_mfma_f32_16x16x32_bf16(a1, b2, acc[H][1][2], 0, 0, 0); \
    acc[H][1][3] = __builtin_amdgcn_mfma_f32_16x16x32_bf16(a1, b3, acc[H][1][3], 0, 0, 0); \
    acc[H][2][0] = __builtin_amdgcn_mfma_f32_16x16x32_bf16(a2, b0, acc[H][2][0], 0, 0, 0); \
    acc[H][2][1] = __builtin_amdgcn_mfma_f32_16x16x32_bf16(a2, b1, acc[H][2][1], 0, 0, 0); \
    acc[H][2][2] = __builtin_amdgcn_mfma_f32_16x16x32_bf16(a2, b2, acc[H][2][2], 0, 0, 0); \
    acc[H][2][3] = __builtin_amdgcn_mfma_f32_16x16x32_bf16(a2, b3, acc[H][2][3], 0, 0, 0); \
    acc[H][3][0] = __builtin_amdgcn_mfma_f32_16x16x32_bf16(a3, b0, acc[H][3][0], 0, 0, 0); \
    acc[H][3][1] = __builtin_amdgcn_mfma_f32_16x16x32_bf16(a3, b1, acc[H][3][1], 0, 0, 0); \
    acc[H][3][2] = __builtin_amdgcn_mfma_f32_16x16x32_bf16(a3, b2, acc[H][3][2], 0, 0, 0); \
    acc[H][3][3] = __builtin_amdgcn_mfma_f32_16x16x32_bf16(a3, b3, acc[H][3][3], 0, 0, 0); \
  } while (0)

template<int KDIM, int NDIM, int EPI, int GATHER>
__device__ __forceinline__ void moe_body(
    const u16* __restrict__ A, const u16* __restrict__ BT,
    const float* __restrict__ bias,
    const int* __restrict__ offsets, const int* __restrict__ counts,
    const int* __restrict__ slot_token, const float* __restrict__ slot_w,
    u16* __restrict__ O16, float* __restrict__ Of) {
  constexpr int NT = KDIM / 64;
  int e = blockIdx.z;
  int cnt = counts[e];
  int rb = blockIdx.y;
  if (rb * 256 >= cnt) return;
  int off = offsets[e];
  int n0 = blockIdx.x * 256;

  __shared__ u16 S[65536];   // 128 KiB

  int tid = threadIdx.x;
  int lane = tid & 63, wave = tid >> 6;
  int wr = wave >> 2, wc = wave & 3;
  int lr = lane & 15, g = lane >> 4;

  const u16* BTe = BT + (size_t)e * NDIM * KDIM;

  const u16* aSrc[2][2];
  const u16* bSrc[2][2];
  int amax = off + cnt - 1;
#pragma unroll
  for (int h = 0; h < 2; h++)
#pragma unroll
    for (int s = 0; s < 2; s++) {
      int c = tid + s * 512;
      int lc = c ^ (((c >> 5) & 1) << 1);
      int ks = lc >> 9, rl = (lc >> 2) & 127, seg = lc & 3;
      int slotRow = off + rb * 256 + h * 128 + rl;
      if (slotRow > amax) slotRow = amax;
      int arow = GATHER ? slot_token[slotRow] : slotRow;
      aSrc[h][s] = A + (size_t)arow * KDIM + ks * 32 + seg * 8;
    }
#pragma unroll
  for (int ks = 0; ks < 2; ks++)
#pragma unroll
    for (int s = 0; s < 2; s++) {
      int c = tid + s * 512;
      int lc = c ^ (((c >> 5) & 1) << 1);
      int row = lc >> 2, seg = lc & 3;
      bSrc[ks][s] = BTe + (size_t)(n0 + row) * KDIM + ks * 32 + seg * 8;
    }

  auto stA = [&](int u, int h) {
    u16* d = &S[(u & 1) * 16384 + h * 8192 + wave * 512];
    gl2lds16(aSrc[h][0] + (size_t)u * 64, d);
    gl2lds16(aSrc[h][1] + (size_t)u * 64, d + 4096);
  };
  auto stB = [&](int u, int ks) {
    u16* d = &S[32768 + (u & 1) * 16384 + ks * 8192 + wave * 512];
    gl2lds16(bSrc[ks][0] + (size_t)u * 64, d);
    gl2lds16(bSrc[ks][1] + (size_t)u * 64, d + 4096);
  };
  auto rdA = [&](int dbuf, int hm, int ks, int i) -> bf16x8 {
    int rl = wr * 64 + i * 16 + lr;
    int logb = ks * 8192 + rl * 64 + g * 16;
    int phys = logb ^ (((rl >> 3) & 1) << 5);
    return *reinterpret_cast<const bf16x8*>(&S[dbuf * 16384 + hm * 8192 + (phys >> 1)]);
  };
  auto rdB = [&](int dbuf, int ks, int j) -> bf16x8 {
    int row = wc * 64 + j * 16 + lr;
    int logb = row * 64 + g * 16;
    int phys = logb ^ (((row >> 3) & 1) << 5);
    return *reinterpret_cast<const bf16x8*>(&S[32768 + dbuf * 16384 + ks * 8192 + (phys >> 1)]);
  };

  f32x4 acc[2][4][4];
#pragma unroll
  for (int h = 0; h < 2; h++)
#pragma unroll
    for (int i = 0; i < 4; i++)
#pragma unroll
      for (int j = 0; j < 4; j++) acc[h][i][j] = (f32x4)(0.0f);

  // prologue: tile0 {Bk0,A0,A1,Bk1}, tile1 {Bk0,A0}; tile0 landed via vmcnt(4)
  stB(0, 0); stA(0, 0); stA(0, 1); stB(0, 1);
  stB(1, 0); stA(1, 0);
  asm volatile("s_waitcnt vmcnt(4)" ::: "memory");
  __builtin_amdgcn_s_barrier();

  bf16x8 b0, b1, b2, b3;
#pragma unroll 2
  for (int t = 0; t < NT; ++t) {
    int dbuf = t & 1;
    // ---- P1 (hm=0, ks=0): stage (t+1).A1
    {
      bf16x8 a0 = rdA(dbuf, 0, 0, 0), a1 = rdA(dbuf, 0, 0, 1),
             a2 = rdA(dbuf, 0, 0, 2), a3 = rdA(dbuf, 0, 0, 3);
      b0 = rdB(dbuf, 0, 0); b1 = rdB(dbuf, 0, 1); b2 = rdB(dbuf, 0, 2); b3 = rdB(dbuf, 0, 3);
      if (t + 1 < NT) stA(t + 1, 1);
      __builtin_amdgcn_s_barrier();
      asm volatile("s_waitcnt lgkmcnt(0)" ::: "memory");
      __builtin_amdgcn_sched_barrier(0);
      __builtin_amdgcn_s_setprio(1);
      MFMA16(0);
      __builtin_amdgcn_s_setprio(0);
      __builtin_amdgcn_s_barrier();
    }
    // ---- P2 (hm=1, ks=0): stage (t+1).Bk1 ; vmcnt(6)
    {
      bf16x8 a0 = rdA(dbuf, 1, 0, 0), a1 = rdA(dbuf, 1, 0, 1),
             a2 = rdA(dbuf, 1, 0, 2), a3 = rdA(dbuf, 1, 0, 3);
      if (t + 1 < NT) {
        stB(t + 1, 1);
        asm volatile("s_waitcnt vmcnt(6)" ::: "memory");
      }
      __builtin_amdgcn_s_barrier();
      asm volatile("s_waitcnt lgkmcnt(0)" ::: "memory");
      __builtin_amdgcn_sched_barrier(0);
      __builtin_amdgcn_s_setprio(1);
      MFMA16(1);
      __builtin_amdgcn_s_setprio(0);
      __builtin_amdgcn_s_barrier();
    }
    // ---- P3 (hm=0, ks=1): stage (t+2).Bk0
    {
      bf16x8 a0 = rdA(dbuf, 0, 1, 0), a1 = rdA(dbuf, 0, 1, 1),
             a2 = rdA(dbuf, 0, 1, 2), a3 = rdA(dbuf, 0, 1, 3);
      b0 = rdB(dbuf, 1, 0); b1 = rdB(dbuf, 1, 1); b2 = rdB(dbuf, 1, 2); b3 = rdB(dbuf, 1, 3);
      if (t + 2 < NT) stB(t + 2, 0);
      __builtin_amdgcn_s_barrier();
      asm volatile("s_waitcnt lgkmcnt(0)" ::: "memory");
      __builtin_amdgcn_sched_barrier(0);
      __builtin_amdgcn_s_setprio(1);
      MFMA16(0);
      __builtin_amdgcn_s_setprio(0);
      __builtin_amdgcn_s_barrier();
    }
    // ---- P4 (hm=1, ks=1): stage (t+2).A0 ; vmcnt(6) (tail: drain)
    {
      bf16x8 a0 = rdA(dbuf, 1, 1, 0), a1 = rdA(dbuf, 1, 1, 1),
             a2 = rdA(dbuf, 1, 1, 2), a3 = rdA(dbuf, 1, 1, 3);
      if (t + 2 < NT) {
        stA(t + 2, 0);
        asm volatile("s_waitcnt vmcnt(6)" ::: "memory");
      } else if (t + 1 < NT) {
        asm volatile("s_waitcnt vmcnt(0)" ::: "memory");
      }
      __builtin_amdgcn_s_barrier();
      asm volatile("s_waitcnt lgkmcnt(0)" ::: "memory");
      __builtin_amdgcn_sched_barrier(0);
      __builtin_amdgcn_s_setprio(1);
      MFMA16(1);
      __builtin_amdgcn_s_setprio(0);
      __builtin_amdgcn_s_barrier();
    }
  }

  int rlim = cnt - rb * 256;
  if (EPI == 2) {
#pragma unroll
    for (int hm = 0; hm < 2; hm++)
#pragma unroll
      for (int i = 0; i < 4; i++)
#pragma unroll
        for (int q = 0; q < 4; q++) {
          int m = hm * 128 + wr * 64 + i * 16 + g * 4 + q;
          if (m < rlim) {
            int slot = off + rb * 256 + m;
#pragma unroll
            for (int j = 0; j < 4; j++) {
              int n = n0 + wc * 64 + j * 16 + lr;
              float v = acc[hm][i][j][q] + bias[e * NDIM + n];
              atomicAdd(Of + (size_t)slot_token[slot] * NDIM + n, v * slot_w[slot]);
            }
          }
        }
  } else {
    // staged epilogue: scale/activate in regs -> LDS (n XOR-swizzled) -> coalesced stores
#pragma unroll
    for (int hm = 0; hm < 2; hm++)
#pragma unroll
      for (int i = 0; i < 4; i++)
#pragma unroll
        for (int q = 0; q < 4; q++) {
          int m = hm * 128 + wr * 64 + i * 16 + g * 4 + q;
          int slot = off + rb * 256 + m;
          float sw = (EPI == 1) ? slot_w[slot] : 0.f;
#pragma unroll
          for (int j = 0; j < 4; j++) {
            int n = wc * 64 + j * 16 + lr;
            float v = acc[hm][i][j][q] + bias[e * NDIM + n0 + n];
            if (EPI == 0) v = v / (1.f + __expf(-v));   // silu (fast exp)
            else          v = v * sw;
            int pn = n ^ (((m >> 2) & 7) << 3);
            S[m * 256 + pn] = f2bf(v);
          }
        }
    __builtin_amdgcn_s_barrier();
    int rgrp = tid >> 5;
    int cs = (tid & 31) * 8;
#pragma unroll
    for (int p = 0; p < 16; p++) {
      int m = rgrp * 16 + p;
      if (m < rlim) {
        int slot = off + rb * 256 + m;
        int pc = cs ^ (((m >> 2) & 7) << 3);
        uint4 vv = *(const uint4*)&S[m * 256 + pc];
        *(uint4*)(O16 + (size_t)slot * NDIM + n0 + cs) = vv;
      }
    }
  }
}

__global__ __launch_bounds__(512, 2) void moe_g1_kernel(
    const u16* __restrict__ A, const u16* __restrict__ BT, const float* __restrict__ bias,
    const int* __restrict__ offsets, const int* __restrict__ counts,
    const int* __restrict__ slot_token, const float* __restrict__ slot_w,
    u16* __restrict__ O16) {
  moe_body<Dd, FFf, 0, 1>(A, BT, bias, offsets, counts, slot_token, slot_w, O16, nullptr);
}
__global__ __launch_bounds__(512, 2) void moe_g2_kernel(
    const u16* __restrict__ A, const u16* __restrict__ BT, const float* __restrict__ bias,
    const int* __restrict__ offsets, const int* __restrict__ counts,
    const int* __restrict__ slot_token, const float* __restrict__ slot_w,
    u16* __restrict__ O16) {
  moe_body<FFf, Dd, 1, 0>(A, BT, bias, offsets, counts, slot_token, slot_w, O16, nullptr);
}
__global__ __launch_bounds__(512, 2) void moe_g2_atomic_kernel(
    const u16* __restrict__ A, const u16* __restrict__ BT, const float* __restrict__ bias,
    const int* __restrict__ offsets, const int* __restrict__ counts,
    const int* __restrict__ slot_token, const float* __restrict__ slot_w,
    float* __restrict__ Of) {
  moe_body<FFf, Dd, 2, 0>(A, BT, bias, offsets, counts, slot_token, slot_w, nullptr, Of);
}

// ---------------- combine: out[t] = y[slot0] + y[slot1] ----------------
__global__ void combine_kernel(const u16* __restrict__ y, const int* __restrict__ tok_slot,
                               float* __restrict__ out) {
  int gid = blockIdx.x * blockDim.x + threadIdx.x;
  int t = gid >> 7;
  int seg = gid & 127;
  int s0 = tok_slot[t * 2 + 0], s1 = tok_slot[t * 2 + 1];
  uint4 a = *(const uint4*)(y + (size_t)s0 * Dd + seg * 8);
  uint4 b = *(const uint4*)(y + (size_t)s1 * Dd + seg * 8);
  f32x4 o0, o1;
  o0[0] = bf2f((u16)a.x) + bf2f((u16)b.x);
  o0[1] = bf2f((u16)(a.x >> 16)) + bf2f((u16)(b.x >> 16));
  o0[2] = bf2f((u16)a.y) + bf2f((u16)b.y);
  o0[3] = bf2f((u16)(a.y >> 16)) + bf2f((u16)(b.y >> 16));
  o1[0] = bf2f((u16)a.z) + bf2f((u16)b.z);
  o1[1] = bf2f((u16)(a.z >> 16)) + bf2f((u16)(b.z >> 16));
  o1[2] = bf2f((u16)a.w) + bf2f((u16)b.w);
  o1[3] = bf2f((u16)(a.w >> 16)) + bf2f((u16)(b.w >> 16));
  float* op = out + (size_t)t * Dd + seg * 8;
  *(f32x4*)op = o0;
  *(f32x4*)(op + 4) = o1;
}

extern "C" void kernel_launch(void* const* d_in, const int* in_sizes, int n_in,
                              void* d_out, int out_size, void* d_ws, size_t ws_size,
                              hipStream_t stream) {
  const float* x  = (const float*)d_in[0];
  const float* gw = (const float*)d_in[1];
  const float* w1 = (const float*)d_in[2];
  const float* b1 = (const float*)d_in[3];
  const float* w2 = (const float*)d_in[4];
  const float* b2 = (const float*)d_in[5];
  float* out = (float*)d_out;

  char* ws = (char*)d_ws;
  size_t off_counts = 0;
  size_t off_offsets = 256;
  size_t off_cursors = 512;
  size_t off_done = 768;
  size_t off_tok_e = 1024;
  size_t off_tok_w     = off_tok_e + (size_t)Tt * 2 * 4;
  size_t off_tok_slot  = off_tok_w + (size_t)Tt * 2 * 4;
  size_t off_slot_token= off_tok_slot + (size_t)Tt * 2 * 4;
  size_t off_slot_w    = off_slot_token + (size_t)SLOTS * 4;
  size_t off_xb        = off_slot_w + (size_t)SLOTS * 4;
  size_t off_h         = off_xb + (size_t)Tt * Dd * 2;
  size_t off_wT        = off_h + (size_t)SLOTS * FFf * 2;
  size_t off_y         = off_wT + (size_t)Ee * Dd * FFf * 2;
  size_t off_wT2       = off_y + (size_t)SLOTS * Dd * 2;
  size_t need_atomic   = off_y;
  size_t need_y        = off_wT2;
  size_t need_merged   = off_wT2 + (size_t)Ee * Dd * FFf * 2;
  if (ws_size < need_atomic) return;  // fail visibly, no OOB
  int tier = (ws_size >= need_merged) ? 2 : (ws_size >= need_y) ? 1 : 0;

  int* counts     = (int*)(ws + off_counts);
  int* offsets    = (int*)(ws + off_offsets);
  int* cursors    = (int*)(ws + off_cursors);
  int* done       = (int*)(ws + off_done);
  int* tok_e      = (int*)(ws + off_tok_e);
  float* tok_w    = (float*)(ws + off_tok_w);
  int* tok_slot   = (int*)(ws + off_tok_slot);
  int* slot_token = (int*)(ws + off_slot_token);
  float* slot_w   = (float*)(ws + off_slot_w);
  u16* xb         = (u16*)(ws + off_xb);
  u16* h          = (u16*)(ws + off_h);
  u16* wT         = (u16*)(ws + off_wT);
  u16* y          = (u16*)(ws + off_y);
  u16* wT2        = (u16*)(ws + off_wT2);

  hipMemsetAsync(ws, 0, 1024, stream);   // counts/offsets/cursors/done

  gate_topk_kernel<<<Tt / 4, 256, 0, stream>>>(x, gw, counts, tok_e, tok_w, xb,
                                               offsets, cursors, done);
  scatter_kernel<<<Tt / 256, 256, 0, stream>>>(tok_e, tok_w, cursors, slot_token, slot_w, tok_slot);

  if (tier == 2) {
    dim3 gc(256, 1, 16);
    wconv2_kernel<<<gc, 256, 0, stream>>>(w1, w2, wT, wT2);
    {
      dim3 g1(FFf / 256, Tt / 256, Ee);
      moe_g1_kernel<<<g1, 512, 0, stream>>>(xb, wT, b1, offsets, counts,
                                            slot_token, slot_w, h);
    }
    {
      dim3 g2(Dd / 256, Tt / 256, Ee);
      moe_g2_kernel<<<g2, 512, 0, stream>>>(h, wT2, b2, offsets, counts,
                                            slot_token, slot_w, y);
    }
    combine_kernel<<<(Tt * 128) / 256, 256, 0, stream>>>(y, tok_slot, out);
  } else if (tier == 1) {
    {
      dim3 gc(FFf / 128, Dd / 128, Ee);
      wconv_kernel<<<gc, 256, 0, stream>>>(w1, wT, Dd, FFf);
    }
    {
      dim3 g1(FFf / 256, Tt / 256, Ee);
      moe_g1_kernel<<<g1, 512, 0, stream>>>(xb, wT, b1, offsets, counts,
                                            slot_token, slot_w, h);
    }
    {
      dim3 gc(Dd / 128, FFf / 128, Ee);
      wconv_kernel<<<gc, 256, 0, stream>>>(w2, wT, FFf, Dd);
    }
    {
      dim3 g2(Dd / 256, Tt / 256, Ee);
      moe_g2_kernel<<<g2, 512, 0, stream>>>(h, wT, b2, offsets, counts,
                                            slot_token, slot_w, y);
    }
    combine_kernel<<<(Tt * 128) / 256, 256, 0, stream>>>(y, tok_slot, out);
  } else {
    hipMemsetAsync(d_out, 0, (size_t)out_size * sizeof(float), stream);
    {
      dim3 gc(FFf / 128, Dd / 128, Ee);
      wconv_kernel<<<gc, 256, 0, stream>>>(w1, wT, Dd, FFf);
    }
    {
      dim3 g1(FFf / 256, Tt / 256, Ee);
      moe_g1_kernel<<<g1, 512, 0, stream>>>(xb, wT, b1, offsets, counts,
                                            slot_token, slot_w, h);
    }
    {
      dim3 gc(Dd / 128, FFf / 128, Ee);
      wconv_kernel<<<gc, 256, 0, stream>>>(w2, wT, FFf, Dd);
    }
    {
      dim3 g2(Dd / 256, Tt / 256, Ee);
      moe_g2_atomic_kernel<<<g2, 512, 0, stream>>>(h, wT, b2, offsets, counts,
                                                   slot_token, slot_w, out);
    }
  }
}

// Round 19
// 752.393 us; speedup vs baseline: 1.1532x; 1.0139x over previous
//
#include <hip/hip_runtime.h>
#include <math.h>

#define Tt 8192             // tokens (B*S)
#define Dd 1024
#define Ee 8
#define FFf 4096
#define SLOTS (Tt*2)

typedef unsigned short u16;
typedef unsigned int u32;
typedef __attribute__((ext_vector_type(8))) __bf16 bf16x8;
typedef __attribute__((ext_vector_type(4))) float f32x4;

__device__ __forceinline__ u16 f2bf(float f) {
  union { float f; u32 u; } v; v.f = f;
  u32 u = v.u;
  return (u16)((u + 0x7FFFu + ((u >> 16) & 1u)) >> 16);
}
__device__ __forceinline__ float bf2f(u16 h) {
  union { u32 u; float f; } v; v.u = ((u32)h) << 16; return v.f;
}
__device__ __forceinline__ void gl2lds16(const u16* g, u16* l) {
  __builtin_amdgcn_global_load_lds((const __attribute__((address_space(1))) void*)g,
                                   (__attribute__((address_space(3))) void*)l, 16, 0, 0);
}

// =====================================================================
// prep_kernel: gate (+x->bf16 convert + last-block scan)  MERGED with
// wconv (both weight transposes). Blocks [0, Tt/4) = gate; blocks
// [Tt/4, Tt/4+4096) = wconv 128x128 tiles. The two halves have no data
// dependence -> gate folds into wconv's scheduling slack, one less launch.
// =====================================================================
__global__ __launch_bounds__(256) void prep_kernel(
    const float* __restrict__ x, const float* __restrict__ gw,
    const float* __restrict__ w1, const float* __restrict__ w2,
    int* __restrict__ counts, int* __restrict__ tok_e, float* __restrict__ tok_w,
    u16* __restrict__ xb, int* __restrict__ offsets, int* __restrict__ cursors,
    int* __restrict__ done, u16* __restrict__ dst1, u16* __restrict__ dst2) {
  __shared__ float t[128][129];
  int bid = blockIdx.x;
  int tid = threadIdx.x;
  if (bid < Tt / 4) {
    // ---------------- gate path ----------------
    int wave = (bid * 256 + tid) >> 6;
    int lane = tid & 63;
    const float* xrow = x + (size_t)wave * Dd;
    int d0 = lane * 16;
    const f32x4* xr4 = (const f32x4*)(xrow + d0);
    f32x4 v0 = xr4[0], v1 = xr4[1], v2 = xr4[2], v3 = xr4[3];
    float xv[16];
#pragma unroll
    for (int k = 0; k < 4; k++) { xv[k] = v0[k]; xv[4 + k] = v1[k]; xv[8 + k] = v2[k]; xv[12 + k] = v3[k]; }
    float p[Ee];
#pragma unroll
    for (int e = 0; e < Ee; e++) p[e] = 0.f;
#pragma unroll
    for (int i = 0; i < 16; i++) {
      const float* g = gw + (size_t)(d0 + i) * Ee;
#pragma unroll
      for (int e = 0; e < Ee; e++) p[e] += xv[i] * g[e];
    }
    {
      uint4 o0, o1;
      o0.x = (u32)f2bf(xv[0]) | ((u32)f2bf(xv[1]) << 16);
      o0.y = (u32)f2bf(xv[2]) | ((u32)f2bf(xv[3]) << 16);
      o0.z = (u32)f2bf(xv[4]) | ((u32)f2bf(xv[5]) << 16);
      o0.w = (u32)f2bf(xv[6]) | ((u32)f2bf(xv[7]) << 16);
      o1.x = (u32)f2bf(xv[8]) | ((u32)f2bf(xv[9]) << 16);
      o1.y = (u32)f2bf(xv[10]) | ((u32)f2bf(xv[11]) << 16);
      o1.z = (u32)f2bf(xv[12]) | ((u32)f2bf(xv[13]) << 16);
      o1.w = (u32)f2bf(xv[14]) | ((u32)f2bf(xv[15]) << 16);
      u16* dp = xb + (size_t)wave * Dd + d0;
      *(uint4*)dp = o0;
      *(uint4*)(dp + 8) = o1;
    }
#pragma unroll
    for (int e = 0; e < Ee; e++) {
      for (int off = 32; off > 0; off >>= 1) p[e] += __shfl_xor(p[e], off, 64);
    }
    if (lane == 0) {
      int e0 = 0; float v0s = p[0];
#pragma unroll
      for (int e = 1; e < Ee; e++) if (p[e] > v0s) { v0s = p[e]; e0 = e; }
      int e1 = -1; float v1s = -INFINITY;
#pragma unroll
      for (int e = 0; e < Ee; e++) if (e != e0 && p[e] > v1s) { v1s = p[e]; e1 = e; }
      float w0 = 1.f / (1.f + expf(v1s - v0s));
      float w1g = 1.f - w0;
      tok_e[wave * 2 + 0] = e0; tok_e[wave * 2 + 1] = e1;
      tok_w[wave * 2 + 0] = w0; tok_w[wave * 2 + 1] = w1g;
      atomicAdd(&counts[e0], 1);
      atomicAdd(&counts[e1], 1);
    }
    __syncthreads();
    if (tid == 0) {
      __threadfence();
      int tk = atomicAdd(done, 1);
      if (tk == Tt / 4 - 1) {
        __threadfence();
        int acc = 0;
        for (int e = 0; e < Ee; e++) { offsets[e] = acc; cursors[e] = acc; acc += counts[e]; }
      }
    }
  } else {
    // ---------------- wconv path (128x128 tiles) ----------------
    int bx = bid - Tt / 4;                    // [0, 4096)
    int half = bx >> 11;                      // 0: w1 (2048 tiles), 1: w2
    int e = (bx >> 8) & 7;
    int tile = bx & 255;
    const float* src = half ? w2 : w1;
    u16* dst = half ? dst2 : dst1;
    int R = half ? FFf : Dd;
    int C = half ? Dd : FFf;
    int cblk = half ? (tile & 7) : (tile & 31);
    int rblk = half ? (tile >> 3) : (tile >> 5);
    size_t ebase = (size_t)e * R * C;
    int r0 = rblk * 128, c0 = cblk * 128;
    int rrow = tid >> 5, rcol = (tid & 31) * 4;
#pragma unroll
    for (int p = 0; p < 16; p++) {
      int row = rrow + p * 8;
      f32x4 v = *(const f32x4*)(src + ebase + (size_t)(r0 + row) * C + c0 + rcol);
      t[row][rcol] = v[0]; t[row][rcol + 1] = v[1]; t[row][rcol + 2] = v[2]; t[row][rcol + 3] = v[3];
    }
    __syncthreads();
    int wcol = tid >> 4, rseg = (tid & 15) * 8;
#pragma unroll
    for (int q = 0; q < 8; q++) {
      int cp = wcol + q * 16;
      float f[8];
#pragma unroll
      for (int i = 0; i < 8; i++) f[i] = t[rseg + i][cp];
      uint4 o;
      o.x = (u32)f2bf(f[0]) | ((u32)f2bf(f[1]) << 16);
      o.y = (u32)f2bf(f[2]) | ((u32)f2bf(f[3]) << 16);
      o.z = (u32)f2bf(f[4]) | ((u32)f2bf(f[5]) << 16);
      o.w = (u32)f2bf(f[6]) | ((u32)f2bf(f[7]) << 16);
      *(uint4*)(dst + ebase + (size_t)(c0 + cp) * R + r0 + rseg) = o;
    }
  }
}

// ---------------- standalone gate (fallback tiers) ----------------
__global__ void gate_topk_kernel(const float* __restrict__ x,
                                 const float* __restrict__ gw,
                                 int* __restrict__ counts,
                                 int* __restrict__ tok_e,
                                 float* __restrict__ tok_w,
                                 u16* __restrict__ xb,
                                 int* __restrict__ offsets,
                                 int* __restrict__ cursors,
                                 int* __restrict__ done) {
  int wave = (int)((blockIdx.x * blockDim.x + threadIdx.x) >> 6);
  int lane = threadIdx.x & 63;
  const float* xrow = x + (size_t)wave * Dd;
  int d0 = lane * 16;
  const f32x4* xr4 = (const f32x4*)(xrow + d0);
  f32x4 v0 = xr4[0], v1 = xr4[1], v2 = xr4[2], v3 = xr4[3];
  float xv[16];
#pragma unroll
  for (int k = 0; k < 4; k++) { xv[k] = v0[k]; xv[4 + k] = v1[k]; xv[8 + k] = v2[k]; xv[12 + k] = v3[k]; }
  float p[Ee];
#pragma unroll
  for (int e = 0; e < Ee; e++) p[e] = 0.f;
#pragma unroll
  for (int i = 0; i < 16; i++) {
    const float* g = gw + (size_t)(d0 + i) * Ee;
#pragma unroll
    for (int e = 0; e < Ee; e++) p[e] += xv[i] * g[e];
  }
  {
    uint4 o0, o1;
    o0.x = (u32)f2bf(xv[0]) | ((u32)f2bf(xv[1]) << 16);
    o0.y = (u32)f2bf(xv[2]) | ((u32)f2bf(xv[3]) << 16);
    o0.z = (u32)f2bf(xv[4]) | ((u32)f2bf(xv[5]) << 16);
    o0.w = (u32)f2bf(xv[6]) | ((u32)f2bf(xv[7]) << 16);
    o1.x = (u32)f2bf(xv[8]) | ((u32)f2bf(xv[9]) << 16);
    o1.y = (u32)f2bf(xv[10]) | ((u32)f2bf(xv[11]) << 16);
    o1.z = (u32)f2bf(xv[12]) | ((u32)f2bf(xv[13]) << 16);
    o1.w = (u32)f2bf(xv[14]) | ((u32)f2bf(xv[15]) << 16);
    u16* dp = xb + (size_t)wave * Dd + d0;
    *(uint4*)dp = o0;
    *(uint4*)(dp + 8) = o1;
  }
#pragma unroll
  for (int e = 0; e < Ee; e++) {
    for (int off = 32; off > 0; off >>= 1) p[e] += __shfl_xor(p[e], off, 64);
  }
  if (lane == 0) {
    int e0 = 0; float v0s = p[0];
#pragma unroll
    for (int e = 1; e < Ee; e++) if (p[e] > v0s) { v0s = p[e]; e0 = e; }
    int e1 = -1; float v1s = -INFINITY;
#pragma unroll
    for (int e = 0; e < Ee; e++) if (e != e0 && p[e] > v1s) { v1s = p[e]; e1 = e; }
    float w0 = 1.f / (1.f + expf(v1s - v0s));
    float w1 = 1.f - w0;
    tok_e[wave * 2 + 0] = e0; tok_e[wave * 2 + 1] = e1;
    tok_w[wave * 2 + 0] = w0; tok_w[wave * 2 + 1] = w1;
    atomicAdd(&counts[e0], 1);
    atomicAdd(&counts[e1], 1);
  }
  __syncthreads();
  if (threadIdx.x == 0) {
    __threadfence();
    int t = atomicAdd(done, 1);
    if (t == (int)gridDim.x - 1) {
      __threadfence();
      int acc = 0;
      for (int e = 0; e < Ee; e++) { offsets[e] = acc; cursors[e] = acc; acc += counts[e]; }
    }
  }
}

// ---------------- standalone wconv (fallback tiers) ----------------
__global__ __launch_bounds__(256) void wconv_kernel(const float* __restrict__ src,
                                                    u16* __restrict__ dst, int R, int C) {
  __shared__ float t[128][129];
  int e = blockIdx.z;
  size_t ebase = (size_t)e * R * C;
  int r0 = blockIdx.y * 128, c0 = blockIdx.x * 128;
  int tid = threadIdx.x;
  int rrow = tid >> 5, rcol = (tid & 31) * 4;
#pragma unroll
  for (int p = 0; p < 16; p++) {
    int row = rrow + p * 8;
    f32x4 v = *(const f32x4*)(src + ebase + (size_t)(r0 + row) * C + c0 + rcol);
    t[row][rcol] = v[0]; t[row][rcol + 1] = v[1]; t[row][rcol + 2] = v[2]; t[row][rcol + 3] = v[3];
  }
  __syncthreads();
  int wcol = tid >> 4, rseg = (tid & 15) * 8;
#pragma unroll
  for (int q = 0; q < 8; q++) {
    int cp = wcol + q * 16;
    float f[8];
#pragma unroll
    for (int i = 0; i < 8; i++) f[i] = t[rseg + i][cp];
    uint4 o;
    o.x = (u32)f2bf(f[0]) | ((u32)f2bf(f[1]) << 16);
    o.y = (u32)f2bf(f[2]) | ((u32)f2bf(f[3]) << 16);
    o.z = (u32)f2bf(f[4]) | ((u32)f2bf(f[5]) << 16);
    o.w = (u32)f2bf(f[6]) | ((u32)f2bf(f[7]) << 16);
    *(uint4*)(dst + ebase + (size_t)(c0 + cp) * R + r0 + rseg) = o;
  }
}

// ---------------- scatter tokens into per-expert slot lists ----------------
__global__ void scatter_kernel(const int* __restrict__ tok_e, const float* __restrict__ tok_w,
                               int* __restrict__ cursors,
                               int* __restrict__ slot_token, float* __restrict__ slot_w,
                               int* __restrict__ tok_slot) {
  int t = blockIdx.x * blockDim.x + threadIdx.x;
  if (t >= Tt) return;
#pragma unroll
  for (int k = 0; k < 2; k++) {
    int e = tok_e[t * 2 + k];
    int pos = atomicAdd(&cursors[e], 1);
    slot_token[pos] = t;
    slot_w[pos] = tok_w[t * 2 + k];
    tok_slot[t * 2 + k] = pos;
  }
}

// =====================================================================
// 4-phase 256x256 grouped GEMM — main loop FROZEN (R12 form); R16
// staged epilogue (EPI 0/1), atomic epilogue (EPI 2, fallback only).
// =====================================================================
#define MFMA16(H)                                                                 \
  do {                                                                            \
    acc[H][0][0] = __builtin_amdgcn_mfma_f32_16x16x32_bf16(a0, b0, acc[H][0][0], 0, 0, 0); \
    acc[H][0][1] = __builtin_amdgcn_mfma_f32_16x16x32_bf16(a0, b1, acc[H][0][1], 0, 0, 0); \
    acc[H][0][2] = __builtin_amdgcn_mfma_f32_16x16x32_bf16(a0, b2, acc[H][0][2], 0, 0, 0); \
    acc[H][0][3] = __builtin_amdgcn_mfma_f32_16x16x32_bf16(a0, b3, acc[H][0][3], 0, 0, 0); \
    acc[H][1][0] = __builtin_amdgcn_mfma_f32_16x16x32_bf16(a1, b0, acc[H][1][0], 0, 0, 0); \
    acc[H][1][1] = __builtin_amdgcn_mfma_f32_16x16x32_bf16(a1, b1, acc[H][1][1], 0, 0, 0); \
    acc[H][1][2] = __builtin_amdgcn_mfma_f32_16x16x32_bf16(a1, b2, acc[H][1][2], 0, 0, 0); \
    acc[H][1][3] = __builtin_amdgcn_mfma_f32_16x16x32_bf16(a1, b3, acc[H][1][3], 0, 0, 0); \
    acc[H][2][0] = __builtin_amdgcn_mfma_f32_16x16x32_bf16(a2, b0, acc[H][2][0], 0, 0, 0); \
    acc[H][2][1] = __builtin_amdgcn_mfma_f32_16x16x32_bf16(a2, b1, acc[H][2][1], 0, 0, 0); \
    acc[H][2][2] = __builtin_amdgcn_mfma_f32_16x16x32_bf16(a2, b2, acc[H][2][2], 0, 0, 0); \
    acc[H][2][3] = __builtin_amdgcn_mfma_f32_16x16x32_bf16(a2, b3, acc[H][2][3], 0, 0, 0); \
    acc[H][3][0] = __builtin_amdgcn_mfma_f32_16x16x32_bf16(a3, b0, acc[H][3][0], 0, 0, 0); \
    acc[H][3][1] = __builtin_amdgcn_mfma_f32_16x16x32_bf16(a3, b1, acc[H][3][1], 0, 0, 0); \
    acc[H][3][2] = __builtin_amdgcn_mfma_f32_16x16x32_bf16(a3, b2, acc[H][3][2], 0, 0, 0); \
    acc[H][3][3] = __builtin_amdgcn_mfma_f32_16x16x32_bf16(a3, b3, acc[H][3][3], 0, 0, 0); \
  } while (0)

template<int KDIM, int NDIM, int EPI, int GATHER>
__device__ __forceinline__ void moe_body(
    const u16* __restrict__ A, const u16* __restrict__ BT,
    const float* __restrict__ bias,
    const int* __restrict__ offsets, const int* __restrict__ counts,
    const int* __restrict__ slot_token, const float* __restrict__ slot_w,
    u16* __restrict__ O16, float* __restrict__ Of) {
  constexpr int NT = KDIM / 64;
  int e = blockIdx.z;
  int cnt = counts[e];
  int rb = blockIdx.y;
  if (rb * 256 >= cnt) return;
  int off = offsets[e];
  int n0 = blockIdx.x * 256;

  __shared__ u16 S[65536];   // 128 KiB

  int tid = threadIdx.x;
  int lane = tid & 63, wave = tid >> 6;
  int wr = wave >> 2, wc = wave & 3;
  int lr = lane & 15, g = lane >> 4;

  const u16* BTe = BT + (size_t)e * NDIM * KDIM;

  const u16* aSrc[2][2];
  const u16* bSrc[2][2];
  int amax = off + cnt - 1;
#pragma unroll
  for (int h = 0; h < 2; h++)
#pragma unroll
    for (int s = 0; s < 2; s++) {
      int c = tid + s * 512;
      int lc = c ^ (((c >> 5) & 1) << 1);
      int ks = lc >> 9, rl = (lc >> 2) & 127, seg = lc & 3;
      int slotRow = off + rb * 256 + h * 128 + rl;
      if (slotRow > amax) slotRow = amax;
      int arow = GATHER ? slot_token[slotRow] : slotRow;
      aSrc[h][s] = A + (size_t)arow * KDIM + ks * 32 + seg * 8;
    }
#pragma unroll
  for (int ks = 0; ks < 2; ks++)
#pragma unroll
    for (int s = 0; s < 2; s++) {
      int c = tid + s * 512;
      int lc = c ^ (((c >> 5) & 1) << 1);
      int row = lc >> 2, seg = lc & 3;
      bSrc[ks][s] = BTe + (size_t)(n0 + row) * KDIM + ks * 32 + seg * 8;
    }

  auto stA = [&](int u, int h) {
    u16* d = &S[(u & 1) * 16384 + h * 8192 + wave * 512];
    gl2lds16(aSrc[h][0] + (size_t)u * 64, d);
    gl2lds16(aSrc[h][1] + (size_t)u * 64, d + 4096);
  };
  auto stB = [&](int u, int ks) {
    u16* d = &S[32768 + (u & 1) * 16384 + ks * 8192 + wave * 512];
    gl2lds16(bSrc[ks][0] + (size_t)u * 64, d);
    gl2lds16(bSrc[ks][1] + (size_t)u * 64, d + 4096);
  };
  auto rdA = [&](int dbuf, int hm, int ks, int i) -> bf16x8 {
    int rl = wr * 64 + i * 16 + lr;
    int logb = ks * 8192 + rl * 64 + g * 16;
    int phys = logb ^ (((rl >> 3) & 1) << 5);
    return *reinterpret_cast<const bf16x8*>(&S[dbuf * 16384 + hm * 8192 + (phys >> 1)]);
  };
  auto rdB = [&](int dbuf, int ks, int j) -> bf16x8 {
    int row = wc * 64 + j * 16 + lr;
    int logb = row * 64 + g * 16;
    int phys = logb ^ (((row >> 3) & 1) << 5);
    return *reinterpret_cast<const bf16x8*>(&S[32768 + dbuf * 16384 + ks * 8192 + (phys >> 1)]);
  };

  f32x4 acc[2][4][4];
#pragma unroll
  for (int h = 0; h < 2; h++)
#pragma unroll
    for (int i = 0; i < 4; i++)
#pragma unroll
      for (int j = 0; j < 4; j++) acc[h][i][j] = (f32x4)(0.0f);

  // prologue: tile0 {Bk0,A0,A1,Bk1}, tile1 {Bk0,A0}; tile0 landed via vmcnt(4)
  stB(0, 0); stA(0, 0); stA(0, 1); stB(0, 1);
  stB(1, 0); stA(1, 0);
  asm volatile("s_waitcnt vmcnt(4)" ::: "memory");
  __builtin_amdgcn_s_barrier();

  bf16x8 b0, b1, b2, b3;
#pragma unroll 2
  for (int t = 0; t < NT; ++t) {
    int dbuf = t & 1;
    // ---- P1 (hm=0, ks=0): stage (t+1).A1
    {
      bf16x8 a0 = rdA(dbuf, 0, 0, 0), a1 = rdA(dbuf, 0, 0, 1),
             a2 = rdA(dbuf, 0, 0, 2), a3 = rdA(dbuf, 0, 0, 3);
      b0 = rdB(dbuf, 0, 0); b1 = rdB(dbuf, 0, 1); b2 = rdB(dbuf, 0, 2); b3 = rdB(dbuf, 0, 3);
      if (t + 1 < NT) stA(t + 1, 1);
      __builtin_amdgcn_s_barrier();
      asm volatile("s_waitcnt lgkmcnt(0)" ::: "memory");
      __builtin_amdgcn_sched_barrier(0);
      __builtin_amdgcn_s_setprio(1);
      MFMA16(0);
      __builtin_amdgcn_s_setprio(0);
      __builtin_amdgcn_s_barrier();
    }
    // ---- P2 (hm=1, ks=0): stage (t+1).Bk1 ; vmcnt(6)
    {
      bf16x8 a0 = rdA(dbuf, 1, 0, 0), a1 = rdA(dbuf, 1, 0, 1),
             a2 = rdA(dbuf, 1, 0, 2), a3 = rdA(dbuf, 1, 0, 3);
      if (t + 1 < NT) {
        stB(t + 1, 1);
        asm volatile("s_waitcnt vmcnt(6)" ::: "memory");
      }
      __builtin_amdgcn_s_barrier();
      asm volatile("s_waitcnt lgkmcnt(0)" ::: "memory");
      __builtin_amdgcn_sched_barrier(0);
      __builtin_amdgcn_s_setprio(1);
      MFMA16(1);
      __builtin_amdgcn_s_setprio(0);
      __builtin_amdgcn_s_barrier();
    }
    // ---- P3 (hm=0, ks=1): stage (t+2).Bk0
    {
      bf16x8 a0 = rdA(dbuf, 0, 1, 0), a1 = rdA(dbuf, 0, 1, 1),
             a2 = rdA(dbuf, 0, 1, 2), a3 = rdA(dbuf, 0, 1, 3);
      b0 = rdB(dbuf, 1, 0); b1 = rdB(dbuf, 1, 1); b2 = rdB(dbuf, 1, 2); b3 = rdB(dbuf, 1, 3);
      if (t + 2 < NT) stB(t + 2, 0);
      __builtin_amdgcn_s_barrier();
      asm volatile("s_waitcnt lgkmcnt(0)" ::: "memory");
      __builtin_amdgcn_sched_barrier(0);
      __builtin_amdgcn_s_setprio(1);
      MFMA16(0);
      __builtin_amdgcn_s_setprio(0);
      __builtin_amdgcn_s_barrier();
    }
    // ---- P4 (hm=1, ks=1): stage (t+2).A0 ; vmcnt(6) (tail: drain)
    {
      bf16x8 a0 = rdA(dbuf, 1, 1, 0), a1 = rdA(dbuf, 1, 1, 1),
             a2 = rdA(dbuf, 1, 1, 2), a3 = rdA(dbuf, 1, 1, 3);
      if (t + 2 < NT) {
        stA(t + 2, 0);
        asm volatile("s_waitcnt vmcnt(6)" ::: "memory");
      } else if (t + 1 < NT) {
        asm volatile("s_waitcnt vmcnt(0)" ::: "memory");
      }
      __builtin_amdgcn_s_barrier();
      asm volatile("s_waitcnt lgkmcnt(0)" ::: "memory");
      __builtin_amdgcn_sched_barrier(0);
      __builtin_amdgcn_s_setprio(1);
      MFMA16(1);
      __builtin_amdgcn_s_setprio(0);
      __builtin_amdgcn_s_barrier();
    }
  }

  int rlim = cnt - rb * 256;
  if (EPI == 2) {
#pragma unroll
    for (int hm = 0; hm < 2; hm++)
#pragma unroll
      for (int i = 0; i < 4; i++)
#pragma unroll
        for (int q = 0; q < 4; q++) {
          int m = hm * 128 + wr * 64 + i * 16 + g * 4 + q;
          if (m < rlim) {
            int slot = off + rb * 256 + m;
#pragma unroll
            for (int j = 0; j < 4; j++) {
              int n = n0 + wc * 64 + j * 16 + lr;
              float v = acc[hm][i][j][q] + bias[e * NDIM + n];
              atomicAdd(Of + (size_t)slot_token[slot] * NDIM + n, v * slot_w[slot]);
            }
          }
        }
  } else {
    // staged epilogue: scale/activate in regs -> LDS (n XOR-swizzled) -> coalesced stores
#pragma unroll
    for (int hm = 0; hm < 2; hm++)
#pragma unroll
      for (int i = 0; i < 4; i++)
#pragma unroll
        for (int q = 0; q < 4; q++) {
          int m = hm * 128 + wr * 64 + i * 16 + g * 4 + q;
          int slot = off + rb * 256 + m;
          float sw = (EPI == 1) ? slot_w[slot] : 0.f;
#pragma unroll
          for (int j = 0; j < 4; j++) {
            int n = wc * 64 + j * 16 + lr;
            float v = acc[hm][i][j][q] + bias[e * NDIM + n0 + n];
            if (EPI == 0) v = v / (1.f + __expf(-v));   // silu (fast exp)
            else          v = v * sw;
            int pn = n ^ (((m >> 2) & 7) << 3);
            S[m * 256 + pn] = f2bf(v);
          }
        }
    __builtin_amdgcn_s_barrier();
    int rgrp = tid >> 5;
    int cs = (tid & 31) * 8;
#pragma unroll
    for (int p = 0; p < 16; p++) {
      int m = rgrp * 16 + p;
      if (m < rlim) {
        int slot = off + rb * 256 + m;
        int pc = cs ^ (((m >> 2) & 7) << 3);
        uint4 vv = *(const uint4*)&S[m * 256 + pc];
        *(uint4*)(O16 + (size_t)slot * NDIM + n0 + cs) = vv;
      }
    }
  }
}

__global__ __launch_bounds__(512, 2) void moe_g1_kernel(
    const u16* __restrict__ A, const u16* __restrict__ BT, const float* __restrict__ bias,
    const int* __restrict__ offsets, const int* __restrict__ counts,
    const int* __restrict__ slot_token, const float* __restrict__ slot_w,
    u16* __restrict__ O16) {
  moe_body<Dd, FFf, 0, 1>(A, BT, bias, offsets, counts, slot_token, slot_w, O16, nullptr);
}
__global__ __launch_bounds__(512, 2) void moe_g2_kernel(
    const u16* __restrict__ A, const u16* __restrict__ BT, const float* __restrict__ bias,
    const int* __restrict__ offsets, const int* __restrict__ counts,
    const int* __restrict__ slot_token, const float* __restrict__ slot_w,
    u16* __restrict__ O16) {
  moe_body<FFf, Dd, 1, 0>(A, BT, bias, offsets, counts, slot_token, slot_w, O16, nullptr);
}
__global__ __launch_bounds__(512, 2) void moe_g2_atomic_kernel(
    const u16* __restrict__ A, const u16* __restrict__ BT, const float* __restrict__ bias,
    const int* __restrict__ offsets, const int* __restrict__ counts,
    const int* __restrict__ slot_token, const float* __restrict__ slot_w,
    float* __restrict__ Of) {
  moe_body<FFf, Dd, 2, 0>(A, BT, bias, offsets, counts, slot_token, slot_w, nullptr, Of);
}

// ---------------- combine: out[t] = y[slot0] + y[slot1] ----------------
__global__ void combine_kernel(const u16* __restrict__ y, const int* __restrict__ tok_slot,
                               float* __restrict__ out) {
  int gid = blockIdx.x * blockDim.x + threadIdx.x;
  int t = gid >> 7;
  int seg = gid & 127;
  int s0 = tok_slot[t * 2 + 0], s1 = tok_slot[t * 2 + 1];
  uint4 a = *(const uint4*)(y + (size_t)s0 * Dd + seg * 8);
  uint4 b = *(const uint4*)(y + (size_t)s1 * Dd + seg * 8);
  f32x4 o0, o1;
  o0[0] = bf2f((u16)a.x) + bf2f((u16)b.x);
  o0[1] = bf2f((u16)(a.x >> 16)) + bf2f((u16)(b.x >> 16));
  o0[2] = bf2f((u16)a.y) + bf2f((u16)b.y);
  o0[3] = bf2f((u16)(a.y >> 16)) + bf2f((u16)(b.y >> 16));
  o1[0] = bf2f((u16)a.z) + bf2f((u16)b.z);
  o1[1] = bf2f((u16)(a.z >> 16)) + bf2f((u16)(b.z >> 16));
  o1[2] = bf2f((u16)a.w) + bf2f((u16)b.w);
  o1[3] = bf2f((u16)(a.w >> 16)) + bf2f((u16)(b.w >> 16));
  float* op = out + (size_t)t * Dd + seg * 8;
  *(f32x4*)op = o0;
  *(f32x4*)(op + 4) = o1;
}

extern "C" void kernel_launch(void* const* d_in, const int* in_sizes, int n_in,
                              void* d_out, int out_size, void* d_ws, size_t ws_size,
                              hipStream_t stream) {
  const float* x  = (const float*)d_in[0];
  const float* gw = (const float*)d_in[1];
  const float* w1 = (const float*)d_in[2];
  const float* b1 = (const float*)d_in[3];
  const float* w2 = (const float*)d_in[4];
  const float* b2 = (const float*)d_in[5];
  float* out = (float*)d_out;

  char* ws = (char*)d_ws;
  size_t off_counts = 0;
  size_t off_offsets = 256;
  size_t off_cursors = 512;
  size_t off_done = 768;
  size_t off_tok_e = 1024;
  size_t off_tok_w     = off_tok_e + (size_t)Tt * 2 * 4;
  size_t off_tok_slot  = off_tok_w + (size_t)Tt * 2 * 4;
  size_t off_slot_token= off_tok_slot + (size_t)Tt * 2 * 4;
  size_t off_slot_w    = off_slot_token + (size_t)SLOTS * 4;
  size_t off_xb        = off_slot_w + (size_t)SLOTS * 4;
  size_t off_h         = off_xb + (size_t)Tt * Dd * 2;
  size_t off_wT        = off_h + (size_t)SLOTS * FFf * 2;
  size_t off_y         = off_wT + (size_t)Ee * Dd * FFf * 2;
  size_t off_wT2       = off_y + (size_t)SLOTS * Dd * 2;
  size_t need_atomic   = off_y;
  size_t need_y        = off_wT2;
  size_t need_merged   = off_wT2 + (size_t)Ee * Dd * FFf * 2;
  if (ws_size < need_atomic) return;  // fail visibly, no OOB
  int tier = (ws_size >= need_merged) ? 2 : (ws_size >= need_y) ? 1 : 0;

  int* counts     = (int*)(ws + off_counts);
  int* offsets    = (int*)(ws + off_offsets);
  int* cursors    = (int*)(ws + off_cursors);
  int* done       = (int*)(ws + off_done);
  int* tok_e      = (int*)(ws + off_tok_e);
  float* tok_w    = (float*)(ws + off_tok_w);
  int* tok_slot   = (int*)(ws + off_tok_slot);
  int* slot_token = (int*)(ws + off_slot_token);
  float* slot_w   = (float*)(ws + off_slot_w);
  u16* xb         = (u16*)(ws + off_xb);
  u16* h          = (u16*)(ws + off_h);
  u16* wT         = (u16*)(ws + off_wT);
  u16* y          = (u16*)(ws + off_y);
  u16* wT2        = (u16*)(ws + off_wT2);

  hipMemsetAsync(ws, 0, 1024, stream);   // counts/offsets/cursors/done

  if (tier == 2) {
    // merged gate + wconv (independent work folded into one launch)
    prep_kernel<<<Tt / 4 + 4096, 256, 0, stream>>>(x, gw, w1, w2, counts, tok_e, tok_w,
                                                   xb, offsets, cursors, done, wT, wT2);
    scatter_kernel<<<Tt / 256, 256, 0, stream>>>(tok_e, tok_w, cursors,
                                                 slot_token, slot_w, tok_slot);
    {
      dim3 g1(FFf / 256, Tt / 256, Ee);
      moe_g1_kernel<<<g1, 512, 0, stream>>>(xb, wT, b1, offsets, counts,
                                            slot_token, slot_w, h);
    }
    {
      dim3 g2(Dd / 256, Tt / 256, Ee);
      moe_g2_kernel<<<g2, 512, 0, stream>>>(h, wT2, b2, offsets, counts,
                                            slot_token, slot_w, y);
    }
    combine_kernel<<<(Tt * 128) / 256, 256, 0, stream>>>(y, tok_slot, out);
  } else if (tier == 1) {
    gate_topk_kernel<<<Tt / 4, 256, 0, stream>>>(x, gw, counts, tok_e, tok_w, xb,
                                                 offsets, cursors, done);
    scatter_kernel<<<Tt / 256, 256, 0, stream>>>(tok_e, tok_w, cursors,
                                                 slot_token, slot_w, tok_slot);
    {
      dim3 gc(FFf / 128, Dd / 128, Ee);
      wconv_kernel<<<gc, 256, 0, stream>>>(w1, wT, Dd, FFf);
    }
    {
      dim3 g1(FFf / 256, Tt / 256, Ee);
      moe_g1_kernel<<<g1, 512, 0, stream>>>(xb, wT, b1, offsets, counts,
                                            slot_token, slot_w, h);
    }
    {
      dim3 gc(Dd / 128, FFf / 128, Ee);
      wconv_kernel<<<gc, 256, 0, stream>>>(w2, wT, FFf, Dd);
    }
    {
      dim3 g2(Dd / 256, Tt / 256, Ee);
      moe_g2_kernel<<<g2, 512, 0, stream>>>(h, wT, b2, offsets, counts,
                                            slot_token, slot_w, y);
    }
    combine_kernel<<<(Tt * 128) / 256, 256, 0, stream>>>(y, tok_slot, out);
  } else {
    hipMemsetAsync(d_out, 0, (size_t)out_size * sizeof(float), stream);
    gate_topk_kernel<<<Tt / 4, 256, 0, stream>>>(x, gw, counts, tok_e, tok_w, xb,
                                                 offsets, cursors, done);
    scatter_kernel<<<Tt / 256, 256, 0, stream>>>(tok_e, tok_w, cursors,
                                                 slot_token, slot_w, tok_slot);
    {
      dim3 gc(FFf / 128, Dd / 128, Ee);
      wconv_kernel<<<gc, 256, 0, stream>>>(w1, wT, Dd, FFf);
    }
    {
      dim3 g1(FFf / 256, Tt / 256, Ee);
      moe_g1_kernel<<<g1, 512, 0, stream>>>(xb, wT, b1, offsets, counts,
                                            slot_token, slot_w, h);
    }
    {
      dim3 gc(Dd / 128, FFf / 128, Ee);
      wconv_kernel<<<gc, 256, 0, stream>>>(w2, wT, FFf, Dd);
    }
    {
      dim3 g2(Dd / 256, Tt / 256, Ee);
      moe_g2_atomic_kernel<<<g2, 512, 0, stream>>>(h, wT, b2, offsets, counts,
                                                   slot_token, slot_w, out);
    }
  }
}

// Round 20
// 747.761 us; speedup vs baseline: 1.1603x; 1.0062x over previous
//
#include <hip/hip_runtime.h>
#include <math.h>

#define Tt 8192             // tokens (B*S)
#define Dd 1024
#define Ee 8
#define FFf 4096
#define SLOTS (Tt*2)

typedef unsigned short u16;
typedef unsigned int u32;
typedef __attribute__((ext_vector_type(8))) __bf16 bf16x8;
typedef __attribute__((ext_vector_type(4))) float f32x4;

__device__ __forceinline__ u16 f2bf(float f) {
  union { float f; u32 u; } v; v.f = f;
  u32 u = v.u;
  return (u16)((u + 0x7FFFu + ((u >> 16) & 1u)) >> 16);
}
__device__ __forceinline__ float bf2f(u16 h) {
  union { u32 u; float f; } v; v.u = ((u32)h) << 16; return v.f;
}
__device__ __forceinline__ void gl2lds16(const u16* g, u16* l) {
  __builtin_amdgcn_global_load_lds((const __attribute__((address_space(1))) void*)g,
                                   (__attribute__((address_space(3))) void*)l, 16, 0, 0);
}

// =====================================================================
// prep_kernel (512 thr): gate (+convert + last-block scan) MERGED with
// wconv. R19 found prep latency-bound at 17% occupancy (256thr x 66KB
// LDS = 2 blk/CU = 8 waves/CU, VALU 4%, HBM 6.5%). 512 thr doubles the
// wave pool at same LDS: 16 waves/CU. Blocks [0,1024) gate (8 tok/blk);
// [1024, 1024+4096) wconv 128x128 tiles.
// =====================================================================
__global__ __launch_bounds__(512) void prep_kernel(
    const float* __restrict__ x, const float* __restrict__ gw,
    const float* __restrict__ w1, const float* __restrict__ w2,
    int* __restrict__ counts, int* __restrict__ tok_e, float* __restrict__ tok_w,
    u16* __restrict__ xb, int* __restrict__ offsets, int* __restrict__ cursors,
    int* __restrict__ done, u16* __restrict__ dst1, u16* __restrict__ dst2) {
  __shared__ float t[128][129];
  int bid = blockIdx.x;
  int tid = threadIdx.x;
  if (bid < Tt / 8) {
    // ---------------- gate path (8 tokens/block) ----------------
    int wave = (bid * 512 + tid) >> 6;
    int lane = tid & 63;
    const float* xrow = x + (size_t)wave * Dd;
    int d0 = lane * 16;
    const f32x4* xr4 = (const f32x4*)(xrow + d0);
    f32x4 v0 = xr4[0], v1 = xr4[1], v2 = xr4[2], v3 = xr4[3];
    float xv[16];
#pragma unroll
    for (int k = 0; k < 4; k++) { xv[k] = v0[k]; xv[4 + k] = v1[k]; xv[8 + k] = v2[k]; xv[12 + k] = v3[k]; }
    float p[Ee];
#pragma unroll
    for (int e = 0; e < Ee; e++) p[e] = 0.f;
#pragma unroll
    for (int i = 0; i < 16; i++) {
      const float* g = gw + (size_t)(d0 + i) * Ee;
#pragma unroll
      for (int e = 0; e < Ee; e++) p[e] += xv[i] * g[e];
    }
    {
      uint4 o0, o1;
      o0.x = (u32)f2bf(xv[0]) | ((u32)f2bf(xv[1]) << 16);
      o0.y = (u32)f2bf(xv[2]) | ((u32)f2bf(xv[3]) << 16);
      o0.z = (u32)f2bf(xv[4]) | ((u32)f2bf(xv[5]) << 16);
      o0.w = (u32)f2bf(xv[6]) | ((u32)f2bf(xv[7]) << 16);
      o1.x = (u32)f2bf(xv[8]) | ((u32)f2bf(xv[9]) << 16);
      o1.y = (u32)f2bf(xv[10]) | ((u32)f2bf(xv[11]) << 16);
      o1.z = (u32)f2bf(xv[12]) | ((u32)f2bf(xv[13]) << 16);
      o1.w = (u32)f2bf(xv[14]) | ((u32)f2bf(xv[15]) << 16);
      u16* dp = xb + (size_t)wave * Dd + d0;
      *(uint4*)dp = o0;
      *(uint4*)(dp + 8) = o1;
    }
#pragma unroll
    for (int e = 0; e < Ee; e++) {
      for (int off = 32; off > 0; off >>= 1) p[e] += __shfl_xor(p[e], off, 64);
    }
    if (lane == 0) {
      int e0 = 0; float v0s = p[0];
#pragma unroll
      for (int e = 1; e < Ee; e++) if (p[e] > v0s) { v0s = p[e]; e0 = e; }
      int e1 = -1; float v1s = -INFINITY;
#pragma unroll
      for (int e = 0; e < Ee; e++) if (e != e0 && p[e] > v1s) { v1s = p[e]; e1 = e; }
      float w0 = 1.f / (1.f + expf(v1s - v0s));
      float w1g = 1.f - w0;
      tok_e[wave * 2 + 0] = e0; tok_e[wave * 2 + 1] = e1;
      tok_w[wave * 2 + 0] = w0; tok_w[wave * 2 + 1] = w1g;
      atomicAdd(&counts[e0], 1);
      atomicAdd(&counts[e1], 1);
    }
    __syncthreads();
    if (tid == 0) {
      __threadfence();
      int tk = atomicAdd(done, 1);
      if (tk == Tt / 8 - 1) {
        __threadfence();
        int acc = 0;
        for (int e = 0; e < Ee; e++) { offsets[e] = acc; cursors[e] = acc; acc += counts[e]; }
      }
    }
  } else {
    // ---------------- wconv path (128x128 tiles, 512 thr) ----------------
    int bx = bid - Tt / 8;                    // [0, 4096)
    int half = bx >> 11;                      // 0: w1 (2048 tiles), 1: w2
    int e = (bx >> 8) & 7;
    int tile = bx & 255;
    const float* src = half ? w2 : w1;
    u16* dst = half ? dst2 : dst1;
    int R = half ? FFf : Dd;
    int C = half ? Dd : FFf;
    int cblk = half ? (tile & 7) : (tile & 31);
    int rblk = half ? (tile >> 3) : (tile >> 5);
    size_t ebase = (size_t)e * R * C;
    int r0 = rblk * 128, c0 = cblk * 128;
    int rrow = tid >> 5, rcol = (tid & 31) * 4;   // 16 rows x 128 cols per phase
#pragma unroll
    for (int p = 0; p < 8; p++) {
      int row = rrow + p * 16;
      f32x4 v = *(const f32x4*)(src + ebase + (size_t)(r0 + row) * C + c0 + rcol);
      t[row][rcol] = v[0]; t[row][rcol + 1] = v[1]; t[row][rcol + 2] = v[2]; t[row][rcol + 3] = v[3];
    }
    __syncthreads();
    int wcol = tid >> 4, rseg = (tid & 15) * 8;   // 32 cols x 16 rsegs per phase
#pragma unroll
    for (int q = 0; q < 4; q++) {
      int cp = wcol + q * 32;
      float f[8];
#pragma unroll
      for (int i = 0; i < 8; i++) f[i] = t[rseg + i][cp];
      uint4 o;
      o.x = (u32)f2bf(f[0]) | ((u32)f2bf(f[1]) << 16);
      o.y = (u32)f2bf(f[2]) | ((u32)f2bf(f[3]) << 16);
      o.z = (u32)f2bf(f[4]) | ((u32)f2bf(f[5]) << 16);
      o.w = (u32)f2bf(f[6]) | ((u32)f2bf(f[7]) << 16);
      *(uint4*)(dst + ebase + (size_t)(c0 + cp) * R + r0 + rseg) = o;
    }
  }
}

// ---------------- standalone gate (fallback tiers) ----------------
__global__ void gate_topk_kernel(const float* __restrict__ x,
                                 const float* __restrict__ gw,
                                 int* __restrict__ counts,
                                 int* __restrict__ tok_e,
                                 float* __restrict__ tok_w,
                                 u16* __restrict__ xb,
                                 int* __restrict__ offsets,
                                 int* __restrict__ cursors,
                                 int* __restrict__ done) {
  int wave = (int)((blockIdx.x * blockDim.x + threadIdx.x) >> 6);
  int lane = threadIdx.x & 63;
  const float* xrow = x + (size_t)wave * Dd;
  int d0 = lane * 16;
  const f32x4* xr4 = (const f32x4*)(xrow + d0);
  f32x4 v0 = xr4[0], v1 = xr4[1], v2 = xr4[2], v3 = xr4[3];
  float xv[16];
#pragma unroll
  for (int k = 0; k < 4; k++) { xv[k] = v0[k]; xv[4 + k] = v1[k]; xv[8 + k] = v2[k]; xv[12 + k] = v3[k]; }
  float p[Ee];
#pragma unroll
  for (int e = 0; e < Ee; e++) p[e] = 0.f;
#pragma unroll
  for (int i = 0; i < 16; i++) {
    const float* g = gw + (size_t)(d0 + i) * Ee;
#pragma unroll
    for (int e = 0; e < Ee; e++) p[e] += xv[i] * g[e];
  }
  {
    uint4 o0, o1;
    o0.x = (u32)f2bf(xv[0]) | ((u32)f2bf(xv[1]) << 16);
    o0.y = (u32)f2bf(xv[2]) | ((u32)f2bf(xv[3]) << 16);
    o0.z = (u32)f2bf(xv[4]) | ((u32)f2bf(xv[5]) << 16);
    o0.w = (u32)f2bf(xv[6]) | ((u32)f2bf(xv[7]) << 16);
    o1.x = (u32)f2bf(xv[8]) | ((u32)f2bf(xv[9]) << 16);
    o1.y = (u32)f2bf(xv[10]) | ((u32)f2bf(xv[11]) << 16);
    o1.z = (u32)f2bf(xv[12]) | ((u32)f2bf(xv[13]) << 16);
    o1.w = (u32)f2bf(xv[14]) | ((u32)f2bf(xv[15]) << 16);
    u16* dp = xb + (size_t)wave * Dd + d0;
    *(uint4*)dp = o0;
    *(uint4*)(dp + 8) = o1;
  }
#pragma unroll
  for (int e = 0; e < Ee; e++) {
    for (int off = 32; off > 0; off >>= 1) p[e] += __shfl_xor(p[e], off, 64);
  }
  if (lane == 0) {
    int e0 = 0; float v0s = p[0];
#pragma unroll
    for (int e = 1; e < Ee; e++) if (p[e] > v0s) { v0s = p[e]; e0 = e; }
    int e1 = -1; float v1s = -INFINITY;
#pragma unroll
    for (int e = 0; e < Ee; e++) if (e != e0 && p[e] > v1s) { v1s = p[e]; e1 = e; }
    float w0 = 1.f / (1.f + expf(v1s - v0s));
    float w1 = 1.f - w0;
    tok_e[wave * 2 + 0] = e0; tok_e[wave * 2 + 1] = e1;
    tok_w[wave * 2 + 0] = w0; tok_w[wave * 2 + 1] = w1;
    atomicAdd(&counts[e0], 1);
    atomicAdd(&counts[e1], 1);
  }
  __syncthreads();
  if (threadIdx.x == 0) {
    __threadfence();
    int t = atomicAdd(done, 1);
    if (t == (int)gridDim.x - 1) {
      __threadfence();
      int acc = 0;
      for (int e = 0; e < Ee; e++) { offsets[e] = acc; cursors[e] = acc; acc += counts[e]; }
    }
  }
}

// ---------------- standalone wconv (fallback tiers) ----------------
__global__ __launch_bounds__(256) void wconv_kernel(const float* __restrict__ src,
                                                    u16* __restrict__ dst, int R, int C) {
  __shared__ float t[128][129];
  int e = blockIdx.z;
  size_t ebase = (size_t)e * R * C;
  int r0 = blockIdx.y * 128, c0 = blockIdx.x * 128;
  int tid = threadIdx.x;
  int rrow = tid >> 5, rcol = (tid & 31) * 4;
#pragma unroll
  for (int p = 0; p < 16; p++) {
    int row = rrow + p * 8;
    f32x4 v = *(const f32x4*)(src + ebase + (size_t)(r0 + row) * C + c0 + rcol);
    t[row][rcol] = v[0]; t[row][rcol + 1] = v[1]; t[row][rcol + 2] = v[2]; t[row][rcol + 3] = v[3];
  }
  __syncthreads();
  int wcol = tid >> 4, rseg = (tid & 15) * 8;
#pragma unroll
  for (int q = 0; q < 8; q++) {
    int cp = wcol + q * 16;
    float f[8];
#pragma unroll
    for (int i = 0; i < 8; i++) f[i] = t[rseg + i][cp];
    uint4 o;
    o.x = (u32)f2bf(f[0]) | ((u32)f2bf(f[1]) << 16);
    o.y = (u32)f2bf(f[2]) | ((u32)f2bf(f[3]) << 16);
    o.z = (u32)f2bf(f[4]) | ((u32)f2bf(f[5]) << 16);
    o.w = (u32)f2bf(f[6]) | ((u32)f2bf(f[7]) << 16);
    *(uint4*)(dst + ebase + (size_t)(c0 + cp) * R + r0 + rseg) = o;
  }
}

// ---------------- scatter tokens into per-expert slot lists ----------------
__global__ void scatter_kernel(const int* __restrict__ tok_e, const float* __restrict__ tok_w,
                               int* __restrict__ cursors,
                               int* __restrict__ slot_token, float* __restrict__ slot_w,
                               int* __restrict__ tok_slot) {
  int t = blockIdx.x * blockDim.x + threadIdx.x;
  if (t >= Tt) return;
#pragma unroll
  for (int k = 0; k < 2; k++) {
    int e = tok_e[t * 2 + k];
    int pos = atomicAdd(&cursors[e], 1);
    slot_token[pos] = t;
    slot_w[pos] = tok_w[t * 2 + k];
    tok_slot[t * 2 + k] = pos;
  }
}

// =====================================================================
// 4-phase 256x256 grouped GEMM — main loop FROZEN (R12 form); R16
// staged epilogue (EPI 0/1), atomic epilogue (EPI 2, fallback only).
// =====================================================================
#define MFMA16(H)                                                                 \
  do {                                                                            \
    acc[H][0][0] = __builtin_amdgcn_mfma_f32_16x16x32_bf16(a0, b0, acc[H][0][0], 0, 0, 0); \
    acc[H][0][1] = __builtin_amdgcn_mfma_f32_16x16x32_bf16(a0, b1, acc[H][0][1], 0, 0, 0); \
    acc[H][0][2] = __builtin_amdgcn_mfma_f32_16x16x32_bf16(a0, b2, acc[H][0][2], 0, 0, 0); \
    acc[H][0][3] = __builtin_amdgcn_mfma_f32_16x16x32_bf16(a0, b3, acc[H][0][3], 0, 0, 0); \
    acc[H][1][0] = __builtin_amdgcn_mfma_f32_16x16x32_bf16(a1, b0, acc[H][1][0], 0, 0, 0); \
    acc[H][1][1] = __builtin_amdgcn_mfma_f32_16x16x32_bf16(a1, b1, acc[H][1][1], 0, 0, 0); \
    acc[H][1][2] = __builtin_amdgcn_mfma_f32_16x16x32_bf16(a1, b2, acc[H][1][2], 0, 0, 0); \
    acc[H][1][3] = __builtin_amdgcn_mfma_f32_16x16x32_bf16(a1, b3, acc[H][1][3], 0, 0, 0); \
    acc[H][2][0] = __builtin_amdgcn_mfma_f32_16x16x32_bf16(a2, b0, acc[H][2][0], 0, 0, 0); \
    acc[H][2][1] = __builtin_amdgcn_mfma_f32_16x16x32_bf16(a2, b1, acc[H][2][1], 0, 0, 0); \
    acc[H][2][2] = __builtin_amdgcn_mfma_f32_16x16x32_bf16(a2, b2, acc[H][2][2], 0, 0, 0); \
    acc[H][2][3] = __builtin_amdgcn_mfma_f32_16x16x32_bf16(a2, b3, acc[H][2][3], 0, 0, 0); \
    acc[H][3][0] = __builtin_amdgcn_mfma_f32_16x16x32_bf16(a3, b0, acc[H][3][0], 0, 0, 0); \
    acc[H][3][1] = __builtin_amdgcn_mfma_f32_16x16x32_bf16(a3, b1, acc[H][3][1], 0, 0, 0); \
    acc[H][3][2] = __builtin_amdgcn_mfma_f32_16x16x32_bf16(a3, b2, acc[H][3][2], 0, 0, 0); \
    acc[H][3][3] = __builtin_amdgcn_mfma_f32_16x16x32_bf16(a3, b3, acc[H][3][3], 0, 0, 0); \
  } while (0)

template<int KDIM, int NDIM, int EPI, int GATHER>
__device__ __forceinline__ void moe_body(
    const u16* __restrict__ A, const u16* __restrict__ BT,
    const float* __restrict__ bias,
    const int* __restrict__ offsets, const int* __restrict__ counts,
    const int* __restrict__ slot_token, const float* __restrict__ slot_w,
    u16* __restrict__ O16, float* __restrict__ Of) {
  constexpr int NT = KDIM / 64;
  int e = blockIdx.z;
  int cnt = counts[e];
  int rb = blockIdx.y;
  if (rb * 256 >= cnt) return;
  int off = offsets[e];
  int n0 = blockIdx.x * 256;

  __shared__ u16 S[65536];   // 128 KiB

  int tid = threadIdx.x;
  int lane = tid & 63, wave = tid >> 6;
  int wr = wave >> 2, wc = wave & 3;
  int lr = lane & 15, g = lane >> 4;

  const u16* BTe = BT + (size_t)e * NDIM * KDIM;

  const u16* aSrc[2][2];
  const u16* bSrc[2][2];
  int amax = off + cnt - 1;
#pragma unroll
  for (int h = 0; h < 2; h++)
#pragma unroll
    for (int s = 0; s < 2; s++) {
      int c = tid + s * 512;
      int lc = c ^ (((c >> 5) & 1) << 1);
      int ks = lc >> 9, rl = (lc >> 2) & 127, seg = lc & 3;
      int slotRow = off + rb * 256 + h * 128 + rl;
      if (slotRow > amax) slotRow = amax;
      int arow = GATHER ? slot_token[slotRow] : slotRow;
      aSrc[h][s] = A + (size_t)arow * KDIM + ks * 32 + seg * 8;
    }
#pragma unroll
  for (int ks = 0; ks < 2; ks++)
#pragma unroll
    for (int s = 0; s < 2; s++) {
      int c = tid + s * 512;
      int lc = c ^ (((c >> 5) & 1) << 1);
      int row = lc >> 2, seg = lc & 3;
      bSrc[ks][s] = BTe + (size_t)(n0 + row) * KDIM + ks * 32 + seg * 8;
    }

  auto stA = [&](int u, int h) {
    u16* d = &S[(u & 1) * 16384 + h * 8192 + wave * 512];
    gl2lds16(aSrc[h][0] + (size_t)u * 64, d);
    gl2lds16(aSrc[h][1] + (size_t)u * 64, d + 4096);
  };
  auto stB = [&](int u, int ks) {
    u16* d = &S[32768 + (u & 1) * 16384 + ks * 8192 + wave * 512];
    gl2lds16(bSrc[ks][0] + (size_t)u * 64, d);
    gl2lds16(bSrc[ks][1] + (size_t)u * 64, d + 4096);
  };
  auto rdA = [&](int dbuf, int hm, int ks, int i) -> bf16x8 {
    int rl = wr * 64 + i * 16 + lr;
    int logb = ks * 8192 + rl * 64 + g * 16;
    int phys = logb ^ (((rl >> 3) & 1) << 5);
    return *reinterpret_cast<const bf16x8*>(&S[dbuf * 16384 + hm * 8192 + (phys >> 1)]);
  };
  auto rdB = [&](int dbuf, int ks, int j) -> bf16x8 {
    int row = wc * 64 + j * 16 + lr;
    int logb = row * 64 + g * 16;
    int phys = logb ^ (((row >> 3) & 1) << 5);
    return *reinterpret_cast<const bf16x8*>(&S[32768 + dbuf * 16384 + ks * 8192 + (phys >> 1)]);
  };

  f32x4 acc[2][4][4];
#pragma unroll
  for (int h = 0; h < 2; h++)
#pragma unroll
    for (int i = 0; i < 4; i++)
#pragma unroll
      for (int j = 0; j < 4; j++) acc[h][i][j] = (f32x4)(0.0f);

  // prologue: tile0 {Bk0,A0,A1,Bk1}, tile1 {Bk0,A0}; tile0 landed via vmcnt(4)
  stB(0, 0); stA(0, 0); stA(0, 1); stB(0, 1);
  stB(1, 0); stA(1, 0);
  asm volatile("s_waitcnt vmcnt(4)" ::: "memory");
  __builtin_amdgcn_s_barrier();

  bf16x8 b0, b1, b2, b3;
#pragma unroll 2
  for (int t = 0; t < NT; ++t) {
    int dbuf = t & 1;
    // ---- P1 (hm=0, ks=0): stage (t+1).A1
    {
      bf16x8 a0 = rdA(dbuf, 0, 0, 0), a1 = rdA(dbuf, 0, 0, 1),
             a2 = rdA(dbuf, 0, 0, 2), a3 = rdA(dbuf, 0, 0, 3);
      b0 = rdB(dbuf, 0, 0); b1 = rdB(dbuf, 0, 1); b2 = rdB(dbuf, 0, 2); b3 = rdB(dbuf, 0, 3);
      if (t + 1 < NT) stA(t + 1, 1);
      __builtin_amdgcn_s_barrier();
      asm volatile("s_waitcnt lgkmcnt(0)" ::: "memory");
      __builtin_amdgcn_sched_barrier(0);
      __builtin_amdgcn_s_setprio(1);
      MFMA16(0);
      __builtin_amdgcn_s_setprio(0);
      __builtin_amdgcn_s_barrier();
    }
    // ---- P2 (hm=1, ks=0): stage (t+1).Bk1 ; vmcnt(6)
    {
      bf16x8 a0 = rdA(dbuf, 1, 0, 0), a1 = rdA(dbuf, 1, 0, 1),
             a2 = rdA(dbuf, 1, 0, 2), a3 = rdA(dbuf, 1, 0, 3);
      if (t + 1 < NT) {
        stB(t + 1, 1);
        asm volatile("s_waitcnt vmcnt(6)" ::: "memory");
      }
      __builtin_amdgcn_s_barrier();
      asm volatile("s_waitcnt lgkmcnt(0)" ::: "memory");
      __builtin_amdgcn_sched_barrier(0);
      __builtin_amdgcn_s_setprio(1);
      MFMA16(1);
      __builtin_amdgcn_s_setprio(0);
      __builtin_amdgcn_s_barrier();
    }
    // ---- P3 (hm=0, ks=1): stage (t+2).Bk0
    {
      bf16x8 a0 = rdA(dbuf, 0, 1, 0), a1 = rdA(dbuf, 0, 1, 1),
             a2 = rdA(dbuf, 0, 1, 2), a3 = rdA(dbuf, 0, 1, 3);
      b0 = rdB(dbuf, 1, 0); b1 = rdB(dbuf, 1, 1); b2 = rdB(dbuf, 1, 2); b3 = rdB(dbuf, 1, 3);
      if (t + 2 < NT) stB(t + 2, 0);
      __builtin_amdgcn_s_barrier();
      asm volatile("s_waitcnt lgkmcnt(0)" ::: "memory");
      __builtin_amdgcn_sched_barrier(0);
      __builtin_amdgcn_s_setprio(1);
      MFMA16(0);
      __builtin_amdgcn_s_setprio(0);
      __builtin_amdgcn_s_barrier();
    }
    // ---- P4 (hm=1, ks=1): stage (t+2).A0 ; vmcnt(6) (tail: drain)
    {
      bf16x8 a0 = rdA(dbuf, 1, 1, 0), a1 = rdA(dbuf, 1, 1, 1),
             a2 = rdA(dbuf, 1, 1, 2), a3 = rdA(dbuf, 1, 1, 3);
      if (t + 2 < NT) {
        stA(t + 2, 0);
        asm volatile("s_waitcnt vmcnt(6)" ::: "memory");
      } else if (t + 1 < NT) {
        asm volatile("s_waitcnt vmcnt(0)" ::: "memory");
      }
      __builtin_amdgcn_s_barrier();
      asm volatile("s_waitcnt lgkmcnt(0)" ::: "memory");
      __builtin_amdgcn_sched_barrier(0);
      __builtin_amdgcn_s_setprio(1);
      MFMA16(1);
      __builtin_amdgcn_s_setprio(0);
      __builtin_amdgcn_s_barrier();
    }
  }

  int rlim = cnt - rb * 256;
  if (EPI == 2) {
#pragma unroll
    for (int hm = 0; hm < 2; hm++)
#pragma unroll
      for (int i = 0; i < 4; i++)
#pragma unroll
        for (int q = 0; q < 4; q++) {
          int m = hm * 128 + wr * 64 + i * 16 + g * 4 + q;
          if (m < rlim) {
            int slot = off + rb * 256 + m;
#pragma unroll
            for (int j = 0; j < 4; j++) {
              int n = n0 + wc * 64 + j * 16 + lr;
              float v = acc[hm][i][j][q] + bias[e * NDIM + n];
              atomicAdd(Of + (size_t)slot_token[slot] * NDIM + n, v * slot_w[slot]);
            }
          }
        }
  } else {
    // staged epilogue: scale/activate in regs -> LDS (n XOR-swizzled) -> coalesced stores
#pragma unroll
    for (int hm = 0; hm < 2; hm++)
#pragma unroll
      for (int i = 0; i < 4; i++)
#pragma unroll
        for (int q = 0; q < 4; q++) {
          int m = hm * 128 + wr * 64 + i * 16 + g * 4 + q;
          int slot = off + rb * 256 + m;
          float sw = (EPI == 1) ? slot_w[slot] : 0.f;
#pragma unroll
          for (int j = 0; j < 4; j++) {
            int n = wc * 64 + j * 16 + lr;
            float v = acc[hm][i][j][q] + bias[e * NDIM + n0 + n];
            if (EPI == 0) v = v / (1.f + __expf(-v));   // silu (fast exp)
            else          v = v * sw;
            int pn = n ^ (((m >> 2) & 7) << 3);
            S[m * 256 + pn] = f2bf(v);
          }
        }
    __builtin_amdgcn_s_barrier();
    int rgrp = tid >> 5;
    int cs = (tid & 31) * 8;
#pragma unroll
    for (int p = 0; p < 16; p++) {
      int m = rgrp * 16 + p;
      if (m < rlim) {
        int slot = off + rb * 256 + m;
        int pc = cs ^ (((m >> 2) & 7) << 3);
        uint4 vv = *(const uint4*)&S[m * 256 + pc];
        *(uint4*)(O16 + (size_t)slot * NDIM + n0 + cs) = vv;
      }
    }
  }
}

__global__ __launch_bounds__(512, 2) void moe_g1_kernel(
    const u16* __restrict__ A, const u16* __restrict__ BT, const float* __restrict__ bias,
    const int* __restrict__ offsets, const int* __restrict__ counts,
    const int* __restrict__ slot_token, const float* __restrict__ slot_w,
    u16* __restrict__ O16) {
  moe_body<Dd, FFf, 0, 1>(A, BT, bias, offsets, counts, slot_token, slot_w, O16, nullptr);
}
__global__ __launch_bounds__(512, 2) void moe_g2_kernel(
    const u16* __restrict__ A, const u16* __restrict__ BT, const float* __restrict__ bias,
    const int* __restrict__ offsets, const int* __restrict__ counts,
    const int* __restrict__ slot_token, const float* __restrict__ slot_w,
    u16* __restrict__ O16) {
  moe_body<FFf, Dd, 1, 0>(A, BT, bias, offsets, counts, slot_token, slot_w, O16, nullptr);
}
__global__ __launch_bounds__(512, 2) void moe_g2_atomic_kernel(
    const u16* __restrict__ A, const u16* __restrict__ BT, const float* __restrict__ bias,
    const int* __restrict__ offsets, const int* __restrict__ counts,
    const int* __restrict__ slot_token, const float* __restrict__ slot_w,
    float* __restrict__ Of) {
  moe_body<FFf, Dd, 2, 0>(A, BT, bias, offsets, counts, slot_token, slot_w, nullptr, Of);
}

// ---------------- combine: out[t] = y[slot0] + y[slot1] ----------------
__global__ void combine_kernel(const u16* __restrict__ y, const int* __restrict__ tok_slot,
                               float* __restrict__ out) {
  int gid = blockIdx.x * blockDim.x + threadIdx.x;
  int t = gid >> 7;
  int seg = gid & 127;
  int s0 = tok_slot[t * 2 + 0], s1 = tok_slot[t * 2 + 1];
  uint4 a = *(const uint4*)(y + (size_t)s0 * Dd + seg * 8);
  uint4 b = *(const uint4*)(y + (size_t)s1 * Dd + seg * 8);
  f32x4 o0, o1;
  o0[0] = bf2f((u16)a.x) + bf2f((u16)b.x);
  o0[1] = bf2f((u16)(a.x >> 16)) + bf2f((u16)(b.x >> 16));
  o0[2] = bf2f((u16)a.y) + bf2f((u16)b.y);
  o0[3] = bf2f((u16)(a.y >> 16)) + bf2f((u16)(b.y >> 16));
  o1[0] = bf2f((u16)a.z) + bf2f((u16)b.z);
  o1[1] = bf2f((u16)(a.z >> 16)) + bf2f((u16)(b.z >> 16));
  o1[2] = bf2f((u16)a.w) + bf2f((u16)b.w);
  o1[3] = bf2f((u16)(a.w >> 16)) + bf2f((u16)(b.w >> 16));
  float* op = out + (size_t)t * Dd + seg * 8;
  *(f32x4*)op = o0;
  *(f32x4*)(op + 4) = o1;
}

extern "C" void kernel_launch(void* const* d_in, const int* in_sizes, int n_in,
                              void* d_out, int out_size, void* d_ws, size_t ws_size,
                              hipStream_t stream) {
  const float* x  = (const float*)d_in[0];
  const float* gw = (const float*)d_in[1];
  const float* w1 = (const float*)d_in[2];
  const float* b1 = (const float*)d_in[3];
  const float* w2 = (const float*)d_in[4];
  const float* b2 = (const float*)d_in[5];
  float* out = (float*)d_out;

  char* ws = (char*)d_ws;
  size_t off_counts = 0;
  size_t off_offsets = 256;
  size_t off_cursors = 512;
  size_t off_done = 768;
  size_t off_tok_e = 1024;
  size_t off_tok_w     = off_tok_e + (size_t)Tt * 2 * 4;
  size_t off_tok_slot  = off_tok_w + (size_t)Tt * 2 * 4;
  size_t off_slot_token= off_tok_slot + (size_t)Tt * 2 * 4;
  size_t off_slot_w    = off_slot_token + (size_t)SLOTS * 4;
  size_t off_xb        = off_slot_w + (size_t)SLOTS * 4;
  size_t off_h         = off_xb + (size_t)Tt * Dd * 2;
  size_t off_wT        = off_h + (size_t)SLOTS * FFf * 2;
  size_t off_y         = off_wT + (size_t)Ee * Dd * FFf * 2;
  size_t off_wT2       = off_y + (size_t)SLOTS * Dd * 2;
  size_t need_atomic   = off_y;
  size_t need_y        = off_wT2;
  size_t need_merged   = off_wT2 + (size_t)Ee * Dd * FFf * 2;
  if (ws_size < need_atomic) return;  // fail visibly, no OOB
  int tier = (ws_size >= need_merged) ? 2 : (ws_size >= need_y) ? 1 : 0;

  int* counts     = (int*)(ws + off_counts);
  int* offsets    = (int*)(ws + off_offsets);
  int* cursors    = (int*)(ws + off_cursors);
  int* done       = (int*)(ws + off_done);
  int* tok_e      = (int*)(ws + off_tok_e);
  float* tok_w    = (float*)(ws + off_tok_w);
  int* tok_slot   = (int*)(ws + off_tok_slot);
  int* slot_token = (int*)(ws + off_slot_token);
  float* slot_w   = (float*)(ws + off_slot_w);
  u16* xb         = (u16*)(ws + off_xb);
  u16* h          = (u16*)(ws + off_h);
  u16* wT         = (u16*)(ws + off_wT);
  u16* y          = (u16*)(ws + off_y);
  u16* wT2        = (u16*)(ws + off_wT2);

  hipMemsetAsync(ws, 0, 1024, stream);   // counts/offsets/cursors/done

  if (tier == 2) {
    prep_kernel<<<Tt / 8 + 4096, 512, 0, stream>>>(x, gw, w1, w2, counts, tok_e, tok_w,
                                                   xb, offsets, cursors, done, wT, wT2);
    scatter_kernel<<<Tt / 256, 256, 0, stream>>>(tok_e, tok_w, cursors,
                                                 slot_token, slot_w, tok_slot);
    {
      dim3 g1(FFf / 256, Tt / 256, Ee);
      moe_g1_kernel<<<g1, 512, 0, stream>>>(xb, wT, b1, offsets, counts,
                                            slot_token, slot_w, h);
    }
    {
      dim3 g2(Dd / 256, Tt / 256, Ee);
      moe_g2_kernel<<<g2, 512, 0, stream>>>(h, wT2, b2, offsets, counts,
                                            slot_token, slot_w, y);
    }
    combine_kernel<<<(Tt * 128) / 256, 256, 0, stream>>>(y, tok_slot, out);
  } else if (tier == 1) {
    gate_topk_kernel<<<Tt / 4, 256, 0, stream>>>(x, gw, counts, tok_e, tok_w, xb,
                                                 offsets, cursors, done);
    scatter_kernel<<<Tt / 256, 256, 0, stream>>>(tok_e, tok_w, cursors,
                                                 slot_token, slot_w, tok_slot);
    {
      dim3 gc(FFf / 128, Dd / 128, Ee);
      wconv_kernel<<<gc, 256, 0, stream>>>(w1, wT, Dd, FFf);
    }
    {
      dim3 g1(FFf / 256, Tt / 256, Ee);
      moe_g1_kernel<<<g1, 512, 0, stream>>>(xb, wT, b1, offsets, counts,
                                            slot_token, slot_w, h);
    }
    {
      dim3 gc(Dd / 128, FFf / 128, Ee);
      wconv_kernel<<<gc, 256, 0, stream>>>(w2, wT, FFf, Dd);
    }
    {
      dim3 g2(Dd / 256, Tt / 256, Ee);
      moe_g2_kernel<<<g2, 512, 0, stream>>>(h, wT, b2, offsets, counts,
                                            slot_token, slot_w, y);
    }
    combine_kernel<<<(Tt * 128) / 256, 256, 0, stream>>>(y, tok_slot, out);
  } else {
    hipMemsetAsync(d_out, 0, (size_t)out_size * sizeof(float), stream);
    gate_topk_kernel<<<Tt / 4, 256, 0, stream>>>(x, gw, counts, tok_e, tok_w, xb,
                                                 offsets, cursors, done);
    scatter_kernel<<<Tt / 256, 256, 0, stream>>>(tok_e, tok_w, cursors,
                                                 slot_token, slot_w, tok_slot);
    {
      dim3 gc(FFf / 128, Dd / 128, Ee);
      wconv_kernel<<<gc, 256, 0, stream>>>(w1, wT, Dd, FFf);
    }
    {
      dim3 g1(FFf / 256, Tt / 256, Ee);
      moe_g1_kernel<<<g1, 512, 0, stream>>>(xb, wT, b1, offsets, counts,
                                            slot_token, slot_w, h);
    }
    {
      dim3 gc(Dd / 128, FFf / 128, Ee);
      wconv_kernel<<<gc, 256, 0, stream>>>(w2, wT, FFf, Dd);
    }
    {
      dim3 g2(Dd / 256, Tt / 256, Ee);
      moe_g2_atomic_kernel<<<g2, 512, 0, stream>>>(h, wT, b2, offsets, counts,
                                                   slot_token, slot_w, out);
    }
  }
}